// Round 5
// baseline (3373.673 us; speedup 1.0000x reference)
//
#include <hip/hip_runtime.h>
#include <hip/hip_bf16.h>

// Problem constants (fixed by reference)
constexpr int kB = 4096;
constexpr int kD = 512;
constexpr int kH = 512;
constexpr int kS = 16;
constexpr int kG = 2048;   // 4*H
constexpr int kChainBlocks = 1024;   // 4/CU * 256 CU — co-residency arithmetic:
                                     // 24KB LDS*4=96<=160KB; launch_bounds(256,4)
                                     // caps VGPR<=128 -> 16 waves/CU. Exact fit.

typedef __attribute__((ext_vector_type(8))) short bf16x8_t;
typedef __attribute__((ext_vector_type(4))) float f32x4_t;

__device__ __forceinline__ short f2bf(float x) {
  __hip_bfloat16 h = __float2bfloat16(x);
  return *reinterpret_cast<short*>(&h);
}
__device__ __forceinline__ float sigm(float x) { return 1.0f / (1.0f + expf(-x)); }

// ---------------- hand-rolled grid barrier (one-shot counter per step) ------
__device__ __forceinline__ void grid_barrier(unsigned* __restrict__ ctr)
{
  __syncthreads();
  if (threadIdx.x == 0) {
    __threadfence();   // release: flush this block's hbuf writes cross-XCD
    __hip_atomic_fetch_add(ctr, 1u, __ATOMIC_ACQ_REL, __HIP_MEMORY_SCOPE_AGENT);
    while (__hip_atomic_load(ctr, __ATOMIC_ACQUIRE, __HIP_MEMORY_SCOPE_AGENT)
           < (unsigned)kChainBlocks) {
      __builtin_amdgcn_s_sleep(2);
    }
    __threadfence();   // acquire: invalidate stale lines before hbuf reads
  }
  __syncthreads();
}

__global__ void bar_init_kernel(unsigned* __restrict__ ctr)
{
  if (threadIdx.x < 16) ctr[threadIdx.x] = 0u;
}

// ---------------- event detection + new_ptr (precision-critical: f32) ------
__global__ void event_kernel(const float* __restrict__ x,
                             const float* __restrict__ edW,
                             const float* __restrict__ edb,
                             const int* __restrict__ ptr,
                             int* __restrict__ ev,
                             float* __restrict__ newptr_out)
{
  int b = blockIdx.x * 4 + (threadIdx.x >> 6);
  int lane = threadIdx.x & 63;
  const float* xr = x + (size_t)b * kD;
  float sum = 0.f;
  for (int k = lane; k < kD; k += 64) sum += xr[k] * edW[k];
  #pragma unroll
  for (int off = 32; off; off >>= 1) sum += __shfl_down(sum, off, 64);
  if (lane == 0) {
    float e = sigm(sum + edb[0]);
    int evt = (e > 0.85f) ? 1 : 0;
    ev[b] = evt;
    newptr_out[b] = (float)((ptr[b] + evt) & (kS - 1));
  }
}

// ---------------- f32 -> bf16 convert (vectorized) --------------------------
__global__ void f2b_kernel(const float* __restrict__ src, short* __restrict__ dst, int n4)
{
  int i = blockIdx.x * blockDim.x + threadIdx.x;
  if (i >= n4) return;
  const float4 v = reinterpret_cast<const float4*>(src)[i];
  short4 o;
  o.x = f2bf(v.x); o.y = f2bf(v.y); o.z = f2bf(v.z); o.w = f2bf(v.w);
  reinterpret_cast<short4*>(dst)[i] = o;
}

// ---------------- pack [W1 | W2] rows into bf16 with gate interleave --------
// Packed output col p:  h = (p>>6)*16 + (p&15),  gate = (p>>4)&3.
// Source row r = gate*512 + h (PyTorch i,f,g,o order).
__global__ void packw_gates_kernel(const float* __restrict__ W1, int w1,
                                   const float* __restrict__ W2, int w2,
                                   short* __restrict__ dst, int total4)
{
  int i = blockIdx.x * blockDim.x + threadIdx.x;
  if (i >= total4) return;
  long e = (long)i * 4;
  int K = w1 + w2;
  long p = e / K;                       // packed row (= output col)
  int col = (int)(e - p * K);
  long r = (long)(((p >> 4) & 3) * 512 + ((p >> 6) << 4) + (p & 15));
  const float* src = (col < w1) ? (W1 + r * (long)w1 + col)
                                : (W2 + r * (long)w2 + (col - w1));
  const float4 v = *reinterpret_cast<const float4*>(src);
  short4 o; o.x=f2bf(v.x); o.y=f2bf(v.y); o.z=f2bf(v.z); o.w=f2bf(v.w);
  *reinterpret_cast<short4*>(dst + e) = o;
}

// packed bias: out[p] = b1[r] (+ b2[r])
__global__ void packbias_kernel(const float* __restrict__ b1, const float* __restrict__ b2,
                                float* __restrict__ o, int n)
{
  int p = blockIdx.x * blockDim.x + threadIdx.x;
  if (p >= n) return;
  int r = ((p >> 4) & 3) * 512 + ((p >> 6) << 4) + (p & 15);
  float v = b1[r];
  if (b2) v += b2[r];
  o[p] = v;
}

// ---------------- slot write + pos_emb add + bf16 staging -------------------
__global__ void slot_update_kernel(const float* __restrict__ slots,
                                   const float* __restrict__ v,
                                   const float* __restrict__ pos_emb,
                                   const int* __restrict__ ptr,
                                   const int* __restrict__ ev,
                                   float* __restrict__ new_slots,
                                   short* __restrict__ slots_pe)
{
  size_t i = (size_t)blockIdx.x * blockDim.x + threadIdx.x;   // one per 4 elems
  size_t e = i * 4;
  int d = (int)(e & (kD - 1));
  size_t bs = e >> 9;
  int s = (int)(bs & (kS - 1));
  size_t b = bs >> 4;
  float4 val;
  if (ev[b] && (ptr[b] == s)) val = *reinterpret_cast<const float4*>(v + (b << 9) + d);
  else                        val = *reinterpret_cast<const float4*>(slots + e);
  *reinterpret_cast<float4*>(new_slots + e) = val;
  const float4 pe = *reinterpret_cast<const float4*>(pos_emb + ((size_t)s << 9) + d);
  short4 o;
  o.x = f2bf(val.x + pe.x); o.y = f2bf(val.y + pe.y);
  o.z = f2bf(val.z + pe.z); o.w = f2bf(val.w + pe.w);
  *reinterpret_cast<short4*>(slots_pe + e) = o;
}

// ---------------- persistent slot-fuser LSTM chain (manual grid barrier) ----
// Grid MUST be kChainBlocks x 256. Each block owns a fixed 128-row x
// 64-packed-col tile (16 h channels, all 4 gates). c lives in registers.
// Per step: phase A (input half, K=512, independent of h) -> grid barrier
// -> phase B (recurrent half, K=512) -> epilogue (c,h update).
__global__ __launch_bounds__(256, 4)
void chain_kernel(const short* __restrict__ slots_pe,
                  const short* __restrict__ W,      // kG x 1024 gate-packed
                  const float* __restrict__ bias,   // kG packed
                  short* __restrict__ hbuf0,
                  short* __restrict__ hbuf1,
                  float* __restrict__ hmem,
                  unsigned* __restrict__ barrier_ctr)
{
  __shared__ short As[128 * 64];
  __shared__ short Ws[64 * 64];
  const int tid  = threadIdx.x;
  const int wave = tid >> 6;
  const int lane = tid & 63;

  // XCD-chunked swizzle (1024 blocks, 8 XCDs, bx-major within chunk)
  const int vid = (blockIdx.x & 7) * 128 + (blockIdx.x >> 3);
  const int bx  = vid >> 5;          // nby = 32
  const int by  = vid & 31;
  const int row0 = bx * 128;
  const int col0 = by * 64;

  const int srow = tid >> 3;         // 0..31
  const int scol = (tid & 7) * 8;    // 16B chunk within 64-elem row

  float bv[4];
  #pragma unroll
  for (int n = 0; n < 4; ++n)
    bv[n] = bias[col0 + n * 16 + (lane & 15)];
  const int hcol = by * 16 + (lane & 15);

  float c_reg[2][4];
  #pragma unroll
  for (int m = 0; m < 2; ++m)
    #pragma unroll
    for (int r = 0; r < 4; ++r) c_reg[m][r] = 0.f;

  for (int s = 0; s < kS; ++s) {
    f32x4_t acc[2][4];
    #pragma unroll
    for (int m = 0; m < 2; ++m)
      #pragma unroll
      for (int n = 0; n < 4; ++n) acc[m][n] = {0.f, 0.f, 0.f, 0.f};

    // ---- phase A: input half (K = 0..511 of packed W) ----
    const short* A = slots_pe + (size_t)s * kD;
    for (int k0 = 0; k0 < 512; k0 += 64) {
      __syncthreads();
      #pragma unroll
      for (int j = 0; j < 4; ++j) {
        const int arow = j * 32 + srow;
        const short* asrc = A + (size_t)(row0 + arow) * (kS * kD) + k0 + scol;
        __builtin_amdgcn_global_load_lds(
            (const __attribute__((address_space(1))) void*)asrc,
            (__attribute__((address_space(3))) void*)&As[arow * 64 + scol], 16, 0, 0);
      }
      #pragma unroll
      for (int j = 0; j < 2; ++j) {
        const int wrow = j * 32 + srow;
        const short* wsrc = W + (size_t)(col0 + wrow) * 1024 + k0 + scol;
        __builtin_amdgcn_global_load_lds(
            (const __attribute__((address_space(1))) void*)wsrc,
            (__attribute__((address_space(3))) void*)&Ws[wrow * 64 + scol], 16, 0, 0);
      }
      __syncthreads();
      #pragma unroll
      for (int kk = 0; kk < 64; kk += 32) {
        bf16x8_t af[2], bfr[4];
        const int kcol = kk + (lane >> 4) * 8;
        const int ar = wave * 32 + (lane & 15);
        const int br = lane & 15;
        #pragma unroll
        for (int m = 0; m < 2; ++m)
          af[m] = *reinterpret_cast<const bf16x8_t*>(&As[(ar + m * 16) * 64 + kcol]);
        #pragma unroll
        for (int n = 0; n < 4; ++n)
          bfr[n] = *reinterpret_cast<const bf16x8_t*>(&Ws[(br + n * 16) * 64 + kcol]);
        #pragma unroll
        for (int m = 0; m < 2; ++m)
          #pragma unroll
          for (int n = 0; n < 4; ++n)
            acc[m][n] = __builtin_amdgcn_mfma_f32_16x16x32_bf16(af[m], bfr[n], acc[m][n], 0, 0, 0);
      }
    }

    // ---- phase B: recurrent half (K = 512..1023 of packed W) ----
    if (s > 0) {
      const short* Hp = (s & 1) ? hbuf0 : hbuf1;   // hbuf[(s-1)&1]
      grid_barrier(barrier_ctr + (s - 1));
      for (int k0 = 0; k0 < 512; k0 += 64) {
        __syncthreads();
        #pragma unroll
        for (int j = 0; j < 4; ++j) {
          const int arow = j * 32 + srow;
          const short* asrc = Hp + (size_t)(row0 + arow) * kH + k0 + scol;
          __builtin_amdgcn_global_load_lds(
              (const __attribute__((address_space(1))) void*)asrc,
              (__attribute__((address_space(3))) void*)&As[arow * 64 + scol], 16, 0, 0);
        }
        #pragma unroll
        for (int j = 0; j < 2; ++j) {
          const int wrow = j * 32 + srow;
          const short* wsrc = W + (size_t)(col0 + wrow) * 1024 + 512 + k0 + scol;
          __builtin_amdgcn_global_load_lds(
              (const __attribute__((address_space(1))) void*)wsrc,
              (__attribute__((address_space(3))) void*)&Ws[wrow * 64 + scol], 16, 0, 0);
        }
        __syncthreads();
        #pragma unroll
        for (int kk = 0; kk < 64; kk += 32) {
          bf16x8_t af[2], bfr[4];
          const int kcol = kk + (lane >> 4) * 8;
          const int ar = wave * 32 + (lane & 15);
          const int br = lane & 15;
          #pragma unroll
          for (int m = 0; m < 2; ++m)
            af[m] = *reinterpret_cast<const bf16x8_t*>(&As[(ar + m * 16) * 64 + kcol]);
          #pragma unroll
          for (int n = 0; n < 4; ++n)
            bfr[n] = *reinterpret_cast<const bf16x8_t*>(&Ws[(br + n * 16) * 64 + kcol]);
          #pragma unroll
          for (int m = 0; m < 2; ++m)
            #pragma unroll
            for (int n = 0; n < 4; ++n)
              acc[m][n] = __builtin_amdgcn_mfma_f32_16x16x32_bf16(af[m], bfr[n], acc[m][n], 0, 0, 0);
        }
      }
    }

    // ---- epilogue: LSTM cell update, c in registers ----
    short* Hout = (s & 1) ? hbuf1 : hbuf0;
    #pragma unroll
    for (int m = 0; m < 2; ++m) {
      const int rbase = row0 + wave * 32 + m * 16 + (lane >> 4) * 4;
      #pragma unroll
      for (int r = 0; r < 4; ++r) {
        const size_t idx = (size_t)(rbase + r) * kH + hcol;
        const float gi = acc[m][0][r] + bv[0];
        const float gf = acc[m][1][r] + bv[1];
        const float gg = acc[m][2][r] + bv[2];
        const float go = acc[m][3][r] + bv[3];
        const float cn = sigm(gf) * c_reg[m][r] + sigm(gi) * tanhf(gg);
        const float hn = sigm(go) * tanhf(cn);
        c_reg[m][r] = cn;
        Hout[idx] = f2bf(hn);
        if (s == kS - 1) hmem[idx] = hn;
      }
    }
  }
}

// ---------------- bf16 MFMA GEMM with fused epilogue (v-GEMM / outer) ------
// Tile 128x64, BK=64. 4 waves all in M. Grid 1-D XCD-chunk swizzled.
// mode 0: C = A@W^T + bias
// mode 2: outer LSTM ew: c_in -> h_out, c_out  (W gate-packed)
__global__ __launch_bounds__(256, 4)
void gemm_fused_kernel(const short* __restrict__ A0, int lda0,
                       const short* __restrict__ A1, int lda1,
                       const short* __restrict__ A2, int lda2,
                       int nseg, const short* __restrict__ W, int ldw,
                       const float* __restrict__ bias, int mode, int nby,
                       float* __restrict__ C, int ldc,
                       const float* __restrict__ c_in,
                       float* __restrict__ h_out, float* __restrict__ c_out)
{
  __shared__ short As[128 * 64];
  __shared__ short Ws[64 * 64];
  const int tid  = threadIdx.x;
  const int wave = tid >> 6;
  const int lane = tid & 63;

  const int nb  = gridDim.x;
  const int vid = (blockIdx.x & 7) * (nb >> 3) + (blockIdx.x >> 3);
  const int bx  = vid / nby;
  const int by  = vid - bx * nby;
  const int row0 = bx * 128;
  const int col0 = by * 64;
  const int K = nseg << 9;

  f32x4_t acc[2][4];
  #pragma unroll
  for (int m = 0; m < 2; ++m)
    #pragma unroll
    for (int n = 0; n < 4; ++n)
      acc[m][n] = {0.f, 0.f, 0.f, 0.f};

  const int srow = tid >> 3;
  const int scol = (tid & 7) * 8;

  for (int k0 = 0; k0 < K; k0 += 64) {
    const int seg = k0 >> 9;
    const int ks  = k0 & 511;
    const short* Ap = (seg == 0) ? A0 : ((seg == 1) ? A1 : A2);
    const int   lda = (seg == 0) ? lda0 : ((seg == 1) ? lda1 : lda2);
    __syncthreads();
    #pragma unroll
    for (int j = 0; j < 4; ++j) {
      const int arow = j * 32 + srow;
      const short* asrc = Ap + (size_t)(row0 + arow) * lda + ks + scol;
      __builtin_amdgcn_global_load_lds(
          (const __attribute__((address_space(1))) void*)asrc,
          (__attribute__((address_space(3))) void*)&As[arow * 64 + scol], 16, 0, 0);
    }
    #pragma unroll
    for (int j = 0; j < 2; ++j) {
      const int wrow = j * 32 + srow;
      const short* wsrc = W + (size_t)(col0 + wrow) * ldw + k0 + scol;
      __builtin_amdgcn_global_load_lds(
          (const __attribute__((address_space(1))) void*)wsrc,
          (__attribute__((address_space(3))) void*)&Ws[wrow * 64 + scol], 16, 0, 0);
    }
    __syncthreads();
    #pragma unroll
    for (int kk = 0; kk < 64; kk += 32) {
      bf16x8_t af[2], bfr[4];
      const int kcol = kk + (lane >> 4) * 8;
      const int ar = wave * 32 + (lane & 15);
      const int br = lane & 15;
      #pragma unroll
      for (int m = 0; m < 2; ++m)
        af[m] = *reinterpret_cast<const bf16x8_t*>(&As[(ar + m * 16) * 64 + kcol]);
      #pragma unroll
      for (int n = 0; n < 4; ++n)
        bfr[n] = *reinterpret_cast<const bf16x8_t*>(&Ws[(br + n * 16) * 64 + kcol]);
      #pragma unroll
      for (int m = 0; m < 2; ++m)
        #pragma unroll
        for (int n = 0; n < 4; ++n)
          acc[m][n] = __builtin_amdgcn_mfma_f32_16x16x32_bf16(af[m], bfr[n], acc[m][n], 0, 0, 0);
    }
  }

  float bv[4];
  #pragma unroll
  for (int n = 0; n < 4; ++n)
    bv[n] = bias[col0 + n * 16 + (lane & 15)];

  if (mode == 0) {
    #pragma unroll
    for (int n = 0; n < 4; ++n) {
      const int col = col0 + n * 16 + (lane & 15);
      #pragma unroll
      for (int m = 0; m < 2; ++m) {
        const int rbase = row0 + wave * 32 + m * 16 + (lane >> 4) * 4;
        #pragma unroll
        for (int r = 0; r < 4; ++r)
          C[(size_t)(rbase + r) * ldc + col] = acc[m][n][r] + bv[n];
      }
    }
    return;
  }

  const int hcol = (col0 >> 6) * 16 + (lane & 15);
  #pragma unroll
  for (int m = 0; m < 2; ++m) {
    const int rbase = row0 + wave * 32 + m * 16 + (lane >> 4) * 4;
    #pragma unroll
    for (int r = 0; r < 4; ++r) {
      const size_t idx = (size_t)(rbase + r) * kH + hcol;
      const float gi = acc[m][0][r] + bv[0];
      const float gf = acc[m][1][r] + bv[1];
      const float gg = acc[m][2][r] + bv[2];
      const float go = acc[m][3][r] + bv[3];
      const float cn = sigm(gf) * c_in[idx] + sigm(gi) * tanhf(gg);
      const float hn = sigm(go) * tanhf(cn);
      c_out[idx] = cn;
      h_out[idx] = hn;
    }
  }
}

// ============================================================================
extern "C" void kernel_launch(void* const* d_in, const int* in_sizes, int n_in,
                              void* d_out, int out_size, void* d_ws, size_t ws_size,
                              hipStream_t stream)
{
  const float* x_t      = (const float*)d_in[0];
  const float* h_lstm   = (const float*)d_in[1];
  const float* c_lstm   = (const float*)d_in[2];
  const float* slots    = (const float*)d_in[3];
  const int*   ptr      = (const int*)  d_in[4];
  const float* value_W  = (const float*)d_in[5];
  const float* value_b  = (const float*)d_in[6];
  const float* ed_W     = (const float*)d_in[7];
  const float* ed_b     = (const float*)d_in[8];
  const float* pos_emb  = (const float*)d_in[9];
  const float* lstm_Wih = (const float*)d_in[10];
  const float* lstm_Whh = (const float*)d_in[11];
  const float* lstm_bih = (const float*)d_in[12];
  const float* lstm_bhh = (const float*)d_in[13];
  const float* Wih      = (const float*)d_in[14];
  const float* bih      = (const float*)d_in[15];
  const float* Whh      = (const float*)d_in[16];

  float* out       = (float*)d_out;
  float* h_new     = out;
  float* c_new     = out + (size_t)kB * kH;
  float* h_mem     = out + (size_t)2 * kB * kH;
  float* new_slots = out + (size_t)3 * kB * kH;
  float* new_ptr   = out + (size_t)3 * kB * kH + (size_t)kB * kS * kD;

  // workspace layout (bytes)
  char* ws = (char*)d_ws;
  size_t off = 0;
  auto alloc = [&](size_t bytes) { void* p = ws + off; off += (bytes + 255) & ~(size_t)255; return p; };
  int*      ev        = (int*)     alloc((size_t)kB * 4);
  unsigned* bar       = (unsigned*)alloc(16 * 4);
  short*    x_b       = (short*)   alloc((size_t)kB * kD * 2);
  short*    hlstm_b   = (short*)   alloc((size_t)kB * kH * 2);
  short*    vW_b      = (short*)   alloc((size_t)kD * kD * 2);
  short*    stepW_b   = (short*)   alloc((size_t)kG * (kD + kH) * 2);
  float*    stepBias  = (float*)   alloc((size_t)kG * 4);
  short*    outerW_b  = (short*)   alloc((size_t)kG * (kD + kH + kH) * 2);
  float*    outerBias = (float*)   alloc((size_t)kG * 4);
  float*    v_f32     = (float*)   alloc((size_t)kB * kD * 4);
  short*    hbuf0     = (short*)   alloc((size_t)kB * kH * 2);
  short*    hbuf1     = (short*)   alloc((size_t)kB * kH * 2);
  short*    slots_pe  = (short*)   alloc((size_t)kB * kS * kD * 2);
  (void)ws_size; (void)in_sizes; (void)n_in; (void)out_size;

  // 0. barrier counters -> 0 (deterministic across replays; ws not re-poisoned)
  bar_init_kernel<<<1, 64, 0, stream>>>(bar);

  // 1. event flags + new_ptr (f32 exact)
  event_kernel<<<kB / 4, 256, 0, stream>>>(x_t, ed_W, ed_b, ptr, ev, new_ptr);

  // 2. conversions / packing
  f2b_kernel<<<(kB * kD / 4 + 255) / 256, 256, 0, stream>>>(x_t, x_b, kB * kD / 4);
  f2b_kernel<<<(kB * kH / 4 + 255) / 256, 256, 0, stream>>>(h_lstm, hlstm_b, kB * kH / 4);
  f2b_kernel<<<(kD * kD / 4 + 255) / 256, 256, 0, stream>>>(value_W, vW_b, kD * kD / 4);
  packw_gates_kernel<<<(kG * 1024 / 4 + 255) / 256, 256, 0, stream>>>(
      lstm_Wih, kD, lstm_Whh, kH, stepW_b, kG * 1024 / 4);
  packw_gates_kernel<<<(kG * 1536 / 4 + 255) / 256, 256, 0, stream>>>(
      Wih, kD + kH, Whh, kH, outerW_b, kG * 1536 / 4);
  packbias_kernel<<<(kG + 255) / 256, 256, 0, stream>>>(lstm_bih, lstm_bhh, stepBias, kG);
  packbias_kernel<<<(kG + 255) / 256, 256, 0, stream>>>(bih, nullptr, outerBias, kG);

  // 3. v = x @ value_W^T + value_b  (mode 0)
  gemm_fused_kernel<<<(kB / 128) * (kD / 64), 256, 0, stream>>>(
      x_b, kD, nullptr, 0, nullptr, 0, 1, vW_b, kD, value_b, 0, kD / 64,
      v_f32, kD, nullptr, nullptr, nullptr);

  // 4. new_slots (f32 out) + slots_pe bf16 staging
  slot_update_kernel<<<(int)((size_t)kB * kS * kD / 4 / 256), 256, 0, stream>>>(
      slots, v_f32, pos_emb, ptr, ev, new_slots, slots_pe);

  // 5. persistent slot-fuser chain (1024 blocks, 4/CU, manual grid barrier)
  chain_kernel<<<kChainBlocks, 256, 0, stream>>>(
      slots_pe, stepW_b, stepBias, hbuf0, hbuf1, h_mem, bar);

  // 6. outer LSTM fused: gates = [x | h_mem | h_lstm] @ [Wih|Whh]^T + bih
  //    h after step 15 lives in hbuf1.
  gemm_fused_kernel<<<(kB / 128) * (kG / 64), 256, 0, stream>>>(
      x_b, kD, hbuf1, kH, hlstm_b, kH, 3, outerW_b, kD + kH + kH, outerBias, 2, kG / 64,
      nullptr, 0, c_lstm, h_new, c_new);
}

// Round 7
// 1282.407 us; speedup vs baseline: 2.6307x; 2.6307x over previous
//
#include <hip/hip_runtime.h>
#include <hip/hip_bf16.h>

// Problem constants (fixed by reference)
constexpr int kB = 4096;
constexpr int kD = 512;
constexpr int kH = 512;
constexpr int kS = 16;
constexpr int kG = 2048;   // 4*H
constexpr int kChainBlocks = 1024;   // 4/CU * 256 CU. 24KB LDS*4=96<=160KB;
                                     // launch_bounds(256,4) caps VGPR<=128.

typedef __attribute__((ext_vector_type(8))) short bf16x8_t;
typedef __attribute__((ext_vector_type(4))) float f32x4_t;

__device__ __forceinline__ short f2bf(float x) {
  __hip_bfloat16 h = __float2bfloat16(x);
  return *reinterpret_cast<short*>(&h);
}
__device__ __forceinline__ float sigm(float x) { return 1.0f / (1.0f + expf(-x)); }

// LDS XOR swizzle (16B-chunk ^ row&7). Staging pre-swizzles the GLOBAL source
// (global_load_lds dest must stay linear, m104/m108); reads apply the same
// involution. kElem must be a multiple of 8.
__device__ __forceinline__ int swz(int row, int kElem) {
  return row * 64 + (((kElem >> 3) ^ (row & 7)) << 3);
}

__global__ void bar_init_kernel(unsigned* __restrict__ ctr, int n)
{
  int i = blockIdx.x * blockDim.x + threadIdx.x;
  if (i < n) ctr[i] = 0u;
}

// ---------------- event detection + new_ptr (precision-critical: f32) ------
__global__ void event_kernel(const float* __restrict__ x,
                             const float* __restrict__ edW,
                             const float* __restrict__ edb,
                             const int* __restrict__ ptr,
                             int* __restrict__ ev,
                             float* __restrict__ newptr_out)
{
  int b = blockIdx.x * 4 + (threadIdx.x >> 6);
  int lane = threadIdx.x & 63;
  const float* xr = x + (size_t)b * kD;
  float sum = 0.f;
  for (int k = lane; k < kD; k += 64) sum += xr[k] * edW[k];
  #pragma unroll
  for (int off = 32; off; off >>= 1) sum += __shfl_down(sum, off, 64);
  if (lane == 0) {
    float e = sigm(sum + edb[0]);
    int evt = (e > 0.85f) ? 1 : 0;
    ev[b] = evt;
    newptr_out[b] = (float)((ptr[b] + evt) & (kS - 1));
  }
}

// ---------------- f32 -> bf16 convert (vectorized) --------------------------
__global__ void f2b_kernel(const float* __restrict__ src, short* __restrict__ dst, int n4)
{
  int i = blockIdx.x * blockDim.x + threadIdx.x;
  if (i >= n4) return;
  const float4 v = reinterpret_cast<const float4*>(src)[i];
  short4 o;
  o.x = f2bf(v.x); o.y = f2bf(v.y); o.z = f2bf(v.z); o.w = f2bf(v.w);
  reinterpret_cast<short4*>(dst)[i] = o;
}

// ---------------- pack [W1 | W2] rows into bf16 with gate interleave --------
// Packed output col p:  h = (p>>6)*16 + (p&15),  gate = (p>>4)&3.
// Source row r = gate*512 + h (PyTorch i,f,g,o order).
__global__ void packw_gates_kernel(const float* __restrict__ W1, int w1,
                                   const float* __restrict__ W2, int w2,
                                   short* __restrict__ dst, int total4)
{
  int i = blockIdx.x * blockDim.x + threadIdx.x;
  if (i >= total4) return;
  long e = (long)i * 4;
  int K = w1 + w2;
  long p = e / K;                       // packed row (= output col)
  int col = (int)(e - p * K);
  long r = (long)(((p >> 4) & 3) * 512 + ((p >> 6) << 4) + (p & 15));
  const float* src = (col < w1) ? (W1 + r * (long)w1 + col)
                                : (W2 + r * (long)w2 + (col - w1));
  const float4 v = *reinterpret_cast<const float4*>(src);
  short4 o; o.x=f2bf(v.x); o.y=f2bf(v.y); o.z=f2bf(v.z); o.w=f2bf(v.w);
  *reinterpret_cast<short4*>(dst + e) = o;
}

// packed bias: out[p] = b1[r] (+ b2[r])
__global__ void packbias_kernel(const float* __restrict__ b1, const float* __restrict__ b2,
                                float* __restrict__ o, int n)
{
  int p = blockIdx.x * blockDim.x + threadIdx.x;
  if (p >= n) return;
  int r = ((p >> 4) & 3) * 512 + ((p >> 6) << 4) + (p & 15);
  float v = b1[r];
  if (b2) v += b2[r];
  o[p] = v;
}

// ---------------- slot write + pos_emb add + bf16 staging -------------------
__global__ void slot_update_kernel(const float* __restrict__ slots,
                                   const float* __restrict__ v,
                                   const float* __restrict__ pos_emb,
                                   const int* __restrict__ ptr,
                                   const int* __restrict__ ev,
                                   float* __restrict__ new_slots,
                                   short* __restrict__ slots_pe)
{
  size_t i = (size_t)blockIdx.x * blockDim.x + threadIdx.x;   // one per 4 elems
  size_t e = i * 4;
  int d = (int)(e & (kD - 1));
  size_t bs = e >> 9;
  int s = (int)(bs & (kS - 1));
  size_t b = bs >> 4;
  float4 val;
  if (ev[b] && (ptr[b] == s)) val = *reinterpret_cast<const float4*>(v + (b << 9) + d);
  else                        val = *reinterpret_cast<const float4*>(slots + e);
  *reinterpret_cast<float4*>(new_slots + e) = val;
  const float4 pe = *reinterpret_cast<const float4*>(pos_emb + ((size_t)s << 9) + d);
  short4 o;
  o.x = f2bf(val.x + pe.x); o.y = f2bf(val.y + pe.y);
  o.z = f2bf(val.z + pe.z); o.w = f2bf(val.w + pe.w);
  *reinterpret_cast<short4*>(slots_pe + e) = o;
}

// ---------------- persistent slot-fuser LSTM chain --------------------------
// Grid MUST be kChainBlocks x 256. Block (bx,by) owns rows [bx*128,+128),
// packed cols [by*64,+64) (= 16 h channels, 4 gates). c in registers.
// Phase B of (bx,by) reads only h rows [bx*128,+128), written by blocks
// (bx,*): per-bx-group barriers of 32 blocks (one-shot counter per step).
// Spin is RELAXED (no cache side-effects); one ACQUIRE fence on exit.
__global__ __launch_bounds__(256, 4)
void chain_kernel(const short* __restrict__ slots_pe,
                  const short* __restrict__ W,      // kG x 1024 gate-packed
                  const float* __restrict__ bias,   // kG packed
                  short* __restrict__ hbuf0,
                  short* __restrict__ hbuf1,
                  float* __restrict__ hmem,
                  unsigned* __restrict__ barrier_ctr)   // 15*32 ctrs, 64B stride
{
  __shared__ short As[128 * 64];
  __shared__ short Ws[64 * 64];
  const int tid  = threadIdx.x;
  const int wave = tid >> 6;
  const int lane = tid & 63;

  // XCD-chunked swizzle: bx-group (32 blocks) lands on one XCD (perf only)
  const int vid = (blockIdx.x & 7) * 128 + (blockIdx.x >> 3);
  const int bx  = vid >> 5;          // nby = 32
  const int by  = vid & 31;
  const int row0 = bx * 128;
  const int col0 = by * 64;

  const int srow   = tid >> 3;                       // 0..31
  const int scol   = (tid & 7) * 8;                  // linear chunk (LDS dest)
  const int schunk = (((tid >> 3) ^ tid) & 7) * 8;   // swizzled chunk (gl src)

  float bv[4];
  #pragma unroll
  for (int n = 0; n < 4; ++n)
    bv[n] = bias[col0 + n * 16 + (lane & 15)];
  const int hcol = by * 16 + (lane & 15);

  float c_reg[2][4];
  #pragma unroll
  for (int m = 0; m < 2; ++m)
    #pragma unroll
    for (int r = 0; r < 4; ++r) c_reg[m][r] = 0.f;

  for (int s = 0; s < kS; ++s) {
    f32x4_t acc[2][4];
    #pragma unroll
    for (int m = 0; m < 2; ++m)
      #pragma unroll
      for (int n = 0; n < 4; ++n) acc[m][n] = {0.f, 0.f, 0.f, 0.f};

    // ---- phase A: input half (K = 0..511 of packed W) ----
    const short* A = slots_pe + (size_t)s * kD;
    for (int k0 = 0; k0 < 512; k0 += 64) {
      __syncthreads();
      #pragma unroll
      for (int j = 0; j < 4; ++j) {
        const int arow = j * 32 + srow;
        const short* asrc = A + (size_t)(row0 + arow) * (kS * kD) + k0 + schunk;
        __builtin_amdgcn_global_load_lds(
            (const __attribute__((address_space(1))) void*)asrc,
            (__attribute__((address_space(3))) void*)&As[arow * 64 + scol], 16, 0, 0);
      }
      #pragma unroll
      for (int j = 0; j < 2; ++j) {
        const int wrow = j * 32 + srow;
        const short* wsrc = W + (size_t)(col0 + wrow) * 1024 + k0 + schunk;
        __builtin_amdgcn_global_load_lds(
            (const __attribute__((address_space(1))) void*)wsrc,
            (__attribute__((address_space(3))) void*)&Ws[wrow * 64 + scol], 16, 0, 0);
      }
      __syncthreads();
      #pragma unroll
      for (int kk = 0; kk < 64; kk += 32) {
        bf16x8_t af[2], bfr[4];
        const int kcol = kk + (lane >> 4) * 8;
        const int ar = wave * 32 + (lane & 15);
        const int br = lane & 15;
        #pragma unroll
        for (int m = 0; m < 2; ++m)
          af[m] = *reinterpret_cast<const bf16x8_t*>(&As[swz(ar + m * 16, kcol)]);
        #pragma unroll
        for (int n = 0; n < 4; ++n)
          bfr[n] = *reinterpret_cast<const bf16x8_t*>(&Ws[swz(br + n * 16, kcol)]);
        #pragma unroll
        for (int m = 0; m < 2; ++m)
          #pragma unroll
          for (int n = 0; n < 4; ++n)
            acc[m][n] = __builtin_amdgcn_mfma_f32_16x16x32_bf16(af[m], bfr[n], acc[m][n], 0, 0, 0);
      }
    }

    // ---- phase B: recurrent half (K = 512..1023 of packed W) ----
    if (s > 0) {
      const short* Hp = (s & 1) ? hbuf0 : hbuf1;   // hbuf[(s-1)&1]
      // per-bx-group barrier (32 blocks), one-shot counter per (step,bx)
      unsigned* ctr = barrier_ctr + (((s - 1) * 32 + bx) << 4);
      __syncthreads();
      if (tid == 0) {
        __hip_atomic_fetch_add(ctr, 1u, __ATOMIC_RELEASE, __HIP_MEMORY_SCOPE_AGENT);
        while (__hip_atomic_load(ctr, __ATOMIC_RELAXED, __HIP_MEMORY_SCOPE_AGENT) < 32u)
          __builtin_amdgcn_s_sleep(2);
        __builtin_amdgcn_fence(__ATOMIC_ACQUIRE, "agent");
      }
      __syncthreads();
      for (int k0 = 0; k0 < 512; k0 += 64) {
        __syncthreads();
        #pragma unroll
        for (int j = 0; j < 4; ++j) {
          const int arow = j * 32 + srow;
          const short* asrc = Hp + (size_t)(row0 + arow) * kH + k0 + schunk;
          __builtin_amdgcn_global_load_lds(
              (const __attribute__((address_space(1))) void*)asrc,
              (__attribute__((address_space(3))) void*)&As[arow * 64 + scol], 16, 0, 0);
        }
        #pragma unroll
        for (int j = 0; j < 2; ++j) {
          const int wrow = j * 32 + srow;
          const short* wsrc = W + (size_t)(col0 + wrow) * 1024 + 512 + k0 + schunk;
          __builtin_amdgcn_global_load_lds(
              (const __attribute__((address_space(1))) void*)wsrc,
              (__attribute__((address_space(3))) void*)&Ws[wrow * 64 + scol], 16, 0, 0);
        }
        __syncthreads();
        #pragma unroll
        for (int kk = 0; kk < 64; kk += 32) {
          bf16x8_t af[2], bfr[4];
          const int kcol = kk + (lane >> 4) * 8;
          const int ar = wave * 32 + (lane & 15);
          const int br = lane & 15;
          #pragma unroll
          for (int m = 0; m < 2; ++m)
            af[m] = *reinterpret_cast<const bf16x8_t*>(&As[swz(ar + m * 16, kcol)]);
          #pragma unroll
          for (int n = 0; n < 4; ++n)
            bfr[n] = *reinterpret_cast<const bf16x8_t*>(&Ws[swz(br + n * 16, kcol)]);
          #pragma unroll
          for (int m = 0; m < 2; ++m)
            #pragma unroll
            for (int n = 0; n < 4; ++n)
              acc[m][n] = __builtin_amdgcn_mfma_f32_16x16x32_bf16(af[m], bfr[n], acc[m][n], 0, 0, 0);
        }
      }
    }

    // ---- epilogue: LSTM cell update, c in registers ----
    short* Hout = (s & 1) ? hbuf1 : hbuf0;
    #pragma unroll
    for (int m = 0; m < 2; ++m) {
      const int rbase = row0 + wave * 32 + m * 16 + (lane >> 4) * 4;
      #pragma unroll
      for (int r = 0; r < 4; ++r) {
        const size_t idx = (size_t)(rbase + r) * kH + hcol;
        const float gi = acc[m][0][r] + bv[0];
        const float gf = acc[m][1][r] + bv[1];
        const float gg = acc[m][2][r] + bv[2];
        const float go = acc[m][3][r] + bv[3];
        const float cn = sigm(gf) * c_reg[m][r] + sigm(gi) * tanhf(gg);
        const float hn = sigm(go) * tanhf(cn);
        c_reg[m][r] = cn;
        Hout[idx] = f2bf(hn);
        if (s == kS - 1) hmem[idx] = hn;
      }
    }
  }
}

// ---------------- bf16 MFMA GEMM with fused epilogue (v-GEMM / outer) ------
// Tile 128x64, BK=64. 4 waves all in M. Grid 1-D XCD-chunk swizzled.
// mode 0: C = A@W^T + bias
// mode 2: outer LSTM ew: c_in -> h_out, c_out  (W gate-packed)
__global__ __launch_bounds__(256, 4)
void gemm_fused_kernel(const short* __restrict__ A0, int lda0,
                       const short* __restrict__ A1, int lda1,
                       const short* __restrict__ A2, int lda2,
                       int nseg, const short* __restrict__ W, int ldw,
                       const float* __restrict__ bias, int mode, int nby,
                       float* __restrict__ C, int ldc,
                       const float* __restrict__ c_in,
                       float* __restrict__ h_out, float* __restrict__ c_out)
{
  __shared__ short As[128 * 64];
  __shared__ short Ws[64 * 64];
  const int tid  = threadIdx.x;
  const int wave = tid >> 6;
  const int lane = tid & 63;

  const int nb  = gridDim.x;
  const int vid = (blockIdx.x & 7) * (nb >> 3) + (blockIdx.x >> 3);
  const int bx  = vid / nby;
  const int by  = vid - bx * nby;
  const int row0 = bx * 128;
  const int col0 = by * 64;
  const int K = nseg << 9;

  f32x4_t acc[2][4];
  #pragma unroll
  for (int m = 0; m < 2; ++m)
    #pragma unroll
    for (int n = 0; n < 4; ++n)
      acc[m][n] = {0.f, 0.f, 0.f, 0.f};

  const int srow   = tid >> 3;
  const int scol   = (tid & 7) * 8;
  const int schunk = (((tid >> 3) ^ tid) & 7) * 8;

  for (int k0 = 0; k0 < K; k0 += 64) {
    const int seg = k0 >> 9;
    const int ks  = k0 & 511;
    const short* Ap = (seg == 0) ? A0 : ((seg == 1) ? A1 : A2);
    const int   lda = (seg == 0) ? lda0 : ((seg == 1) ? lda1 : lda2);
    __syncthreads();
    #pragma unroll
    for (int j = 0; j < 4; ++j) {
      const int arow = j * 32 + srow;
      const short* asrc = Ap + (size_t)(row0 + arow) * lda + ks + schunk;
      __builtin_amdgcn_global_load_lds(
          (const __attribute__((address_space(1))) void*)asrc,
          (__attribute__((address_space(3))) void*)&As[arow * 64 + scol], 16, 0, 0);
    }
    #pragma unroll
    for (int j = 0; j < 2; ++j) {
      const int wrow = j * 32 + srow;
      const short* wsrc = W + (size_t)(col0 + wrow) * ldw + k0 + schunk;
      __builtin_amdgcn_global_load_lds(
          (const __attribute__((address_space(1))) void*)wsrc,
          (__attribute__((address_space(3))) void*)&Ws[wrow * 64 + scol], 16, 0, 0);
    }
    __syncthreads();
    #pragma unroll
    for (int kk = 0; kk < 64; kk += 32) {
      bf16x8_t af[2], bfr[4];
      const int kcol = kk + (lane >> 4) * 8;
      const int ar = wave * 32 + (lane & 15);
      const int br = lane & 15;
      #pragma unroll
      for (int m = 0; m < 2; ++m)
        af[m] = *reinterpret_cast<const bf16x8_t*>(&As[swz(ar + m * 16, kcol)]);
      #pragma unroll
      for (int n = 0; n < 4; ++n)
        bfr[n] = *reinterpret_cast<const bf16x8_t*>(&Ws[swz(br + n * 16, kcol)]);
      #pragma unroll
      for (int m = 0; m < 2; ++m)
        #pragma unroll
        for (int n = 0; n < 4; ++n)
          acc[m][n] = __builtin_amdgcn_mfma_f32_16x16x32_bf16(af[m], bfr[n], acc[m][n], 0, 0, 0);
    }
  }

  float bv[4];
  #pragma unroll
  for (int n = 0; n < 4; ++n)
    bv[n] = bias[col0 + n * 16 + (lane & 15)];

  if (mode == 0) {
    #pragma unroll
    for (int n = 0; n < 4; ++n) {
      const int col = col0 + n * 16 + (lane & 15);
      #pragma unroll
      for (int m = 0; m < 2; ++m) {
        const int rbase = row0 + wave * 32 + m * 16 + (lane >> 4) * 4;
        #pragma unroll
        for (int r = 0; r < 4; ++r)
          C[(size_t)(rbase + r) * ldc + col] = acc[m][n][r] + bv[n];
      }
    }
    return;
  }

  const int hcol = (col0 >> 6) * 16 + (lane & 15);
  #pragma unroll
  for (int m = 0; m < 2; ++m) {
    const int rbase = row0 + wave * 32 + m * 16 + (lane >> 4) * 4;
    #pragma unroll
    for (int r = 0; r < 4; ++r) {
      const size_t idx = (size_t)(rbase + r) * kH + hcol;
      const float gi = acc[m][0][r] + bv[0];
      const float gf = acc[m][1][r] + bv[1];
      const float gg = acc[m][2][r] + bv[2];
      const float go = acc[m][3][r] + bv[3];
      const float cn = sigm(gf) * c_in[idx] + sigm(gi) * tanhf(gg);
      const float hn = sigm(go) * tanhf(cn);
      c_out[idx] = cn;
      h_out[idx] = hn;
    }
  }
}

// ============================================================================
extern "C" void kernel_launch(void* const* d_in, const int* in_sizes, int n_in,
                              void* d_out, int out_size, void* d_ws, size_t ws_size,
                              hipStream_t stream)
{
  const float* x_t      = (const float*)d_in[0];
  const float* h_lstm   = (const float*)d_in[1];
  const float* c_lstm   = (const float*)d_in[2];
  const float* slots    = (const float*)d_in[3];
  const int*   ptr      = (const int*)  d_in[4];
  const float* value_W  = (const float*)d_in[5];
  const float* value_b  = (const float*)d_in[6];
  const float* ed_W     = (const float*)d_in[7];
  const float* ed_b     = (const float*)d_in[8];
  const float* pos_emb  = (const float*)d_in[9];
  const float* lstm_Wih = (const float*)d_in[10];
  const float* lstm_Whh = (const float*)d_in[11];
  const float* lstm_bih = (const float*)d_in[12];
  const float* lstm_bhh = (const float*)d_in[13];
  const float* Wih      = (const float*)d_in[14];
  const float* bih      = (const float*)d_in[15];
  const float* Whh      = (const float*)d_in[16];

  float* out       = (float*)d_out;
  float* h_new     = out;
  float* c_new     = out + (size_t)kB * kH;
  float* h_mem     = out + (size_t)2 * kB * kH;
  float* new_slots = out + (size_t)3 * kB * kH;
  float* new_ptr   = out + (size_t)3 * kB * kH + (size_t)kB * kS * kD;

  // workspace layout (bytes)
  char* ws = (char*)d_ws;
  size_t off = 0;
  auto alloc = [&](size_t bytes) { void* p = ws + off; off += (bytes + 255) & ~(size_t)255; return p; };
  int*      ev        = (int*)     alloc((size_t)kB * 4);
  unsigned* bar       = (unsigned*)alloc((size_t)15 * 32 * 16 * 4);  // 64B-strided
  short*    x_b       = (short*)   alloc((size_t)kB * kD * 2);
  short*    hlstm_b   = (short*)   alloc((size_t)kB * kH * 2);
  short*    vW_b      = (short*)   alloc((size_t)kD * kD * 2);
  short*    stepW_b   = (short*)   alloc((size_t)kG * (kD + kH) * 2);
  float*    stepBias  = (float*)   alloc((size_t)kG * 4);
  short*    outerW_b  = (short*)   alloc((size_t)kG * (kD + kH + kH) * 2);
  float*    outerBias = (float*)   alloc((size_t)kG * 4);
  float*    v_f32     = (float*)   alloc((size_t)kB * kD * 4);
  short*    hbuf0     = (short*)   alloc((size_t)kB * kH * 2);
  short*    hbuf1     = (short*)   alloc((size_t)kB * kH * 2);
  short*    slots_pe  = (short*)   alloc((size_t)kB * kS * kD * 2);
  (void)ws_size; (void)in_sizes; (void)n_in; (void)out_size;

  // 0. barrier counters -> 0 (one-shot per call; ws not re-poisoned between replays)
  bar_init_kernel<<<(15 * 32 * 16 + 255) / 256, 256, 0, stream>>>(bar, 15 * 32 * 16);

  // 1. event flags + new_ptr (f32 exact)
  event_kernel<<<kB / 4, 256, 0, stream>>>(x_t, ed_W, ed_b, ptr, ev, new_ptr);

  // 2. conversions / packing
  f2b_kernel<<<(kB * kD / 4 + 255) / 256, 256, 0, stream>>>(x_t, x_b, kB * kD / 4);
  f2b_kernel<<<(kB * kH / 4 + 255) / 256, 256, 0, stream>>>(h_lstm, hlstm_b, kB * kH / 4);
  f2b_kernel<<<(kD * kD / 4 + 255) / 256, 256, 0, stream>>>(value_W, vW_b, kD * kD / 4);
  packw_gates_kernel<<<(kG * 1024 / 4 + 255) / 256, 256, 0, stream>>>(
      lstm_Wih, kD, lstm_Whh, kH, stepW_b, kG * 1024 / 4);
  packw_gates_kernel<<<(kG * 1536 / 4 + 255) / 256, 256, 0, stream>>>(
      Wih, kD + kH, Whh, kH, outerW_b, kG * 1536 / 4);
  packbias_kernel<<<(kG + 255) / 256, 256, 0, stream>>>(lstm_bih, lstm_bhh, stepBias, kG);
  packbias_kernel<<<(kG + 255) / 256, 256, 0, stream>>>(bih, nullptr, outerBias, kG);

  // 3. v = x @ value_W^T + value_b  (mode 0)
  gemm_fused_kernel<<<(kB / 128) * (kD / 64), 256, 0, stream>>>(
      x_b, kD, nullptr, 0, nullptr, 0, 1, vW_b, kD, value_b, 0, kD / 64,
      v_f32, kD, nullptr, nullptr, nullptr);

  // 4. new_slots (f32 out) + slots_pe bf16 staging
  slot_update_kernel<<<(int)((size_t)kB * kS * kD / 4 / 256), 256, 0, stream>>>(
      slots, v_f32, pos_emb, ptr, ev, new_slots, slots_pe);

  // 5. persistent slot-fuser chain (1024 blocks, 4/CU, per-bx group barriers)
  chain_kernel<<<kChainBlocks, 256, 0, stream>>>(
      slots_pe, stepW_b, stepBias, hbuf0, hbuf1, h_mem, bar);

  // 6. outer LSTM fused: gates = [x | h_mem | h_lstm] @ [Wih|Whh]^T + bih
  //    h after step 15 lives in hbuf1.
  gemm_fused_kernel<<<(kB / 128) * (kG / 64), 256, 0, stream>>>(
      x_b, kD, hbuf1, kH, hlstm_b, kH, 3, outerW_b, kD + kH + kH, outerBias, 2, kG / 64,
      nullptr, 0, c_lstm, h_new, c_new);
}

// Round 8
// 817.265 us; speedup vs baseline: 4.1280x; 1.5691x over previous
//
#include <hip/hip_runtime.h>
#include <hip/hip_bf16.h>

// Problem constants (fixed by reference)
constexpr int kB = 4096;
constexpr int kD = 512;
constexpr int kH = 512;
constexpr int kS = 16;
constexpr int kG = 2048;   // 4*H
constexpr int kChainBlocks = 1024;   // 4/CU * 256 CU. 24KB LDS*4=96<=160KB;
                                     // launch_bounds(256,4) caps VGPR<=128.

typedef __attribute__((ext_vector_type(8))) short bf16x8_t;
typedef __attribute__((ext_vector_type(4))) float f32x4_t;

__device__ __forceinline__ short f2bf(float x) {
  __hip_bfloat16 h = __float2bfloat16(x);
  return *reinterpret_cast<short*>(&h);
}
__device__ __forceinline__ float sigm(float x) { return 1.0f / (1.0f + expf(-x)); }

// LDS XOR swizzle (16B-chunk ^ row&7). Staging pre-swizzles the GLOBAL source
// (global_load_lds dest must stay linear, m104/m108); reads apply the same
// involution. kElem must be a multiple of 8.
__device__ __forceinline__ int swz(int row, int kElem) {
  return row * 64 + (((kElem >> 3) ^ (row & 7)) << 3);
}

__global__ void bar_init_kernel(unsigned* __restrict__ ctr, int n)
{
  int i = blockIdx.x * blockDim.x + threadIdx.x;
  if (i < n) ctr[i] = 0u;
}

// ---------------- event detection + new_ptr (precision-critical: f32) ------
__global__ void event_kernel(const float* __restrict__ x,
                             const float* __restrict__ edW,
                             const float* __restrict__ edb,
                             const int* __restrict__ ptr,
                             int* __restrict__ ev,
                             float* __restrict__ newptr_out)
{
  int b = blockIdx.x * 4 + (threadIdx.x >> 6);
  int lane = threadIdx.x & 63;
  const float* xr = x + (size_t)b * kD;
  float sum = 0.f;
  for (int k = lane; k < kD; k += 64) sum += xr[k] * edW[k];
  #pragma unroll
  for (int off = 32; off; off >>= 1) sum += __shfl_down(sum, off, 64);
  if (lane == 0) {
    float e = sigm(sum + edb[0]);
    int evt = (e > 0.85f) ? 1 : 0;
    ev[b] = evt;
    newptr_out[b] = (float)((ptr[b] + evt) & (kS - 1));
  }
}

// ---------------- f32 -> bf16 convert (vectorized) --------------------------
__global__ void f2b_kernel(const float* __restrict__ src, short* __restrict__ dst, int n4)
{
  int i = blockIdx.x * blockDim.x + threadIdx.x;
  if (i >= n4) return;
  const float4 v = reinterpret_cast<const float4*>(src)[i];
  short4 o;
  o.x = f2bf(v.x); o.y = f2bf(v.y); o.z = f2bf(v.z); o.w = f2bf(v.w);
  reinterpret_cast<short4*>(dst)[i] = o;
}

// ---------------- pack [W1 | W2] rows into bf16 with gate interleave --------
// Packed output col p:  h = (p>>6)*16 + (p&15),  gate = (p>>4)&3.
// Source row r = gate*512 + h (PyTorch i,f,g,o order).
__global__ void packw_gates_kernel(const float* __restrict__ W1, int w1,
                                   const float* __restrict__ W2, int w2,
                                   short* __restrict__ dst, int total4)
{
  int i = blockIdx.x * blockDim.x + threadIdx.x;
  if (i >= total4) return;
  long e = (long)i * 4;
  int K = w1 + w2;
  long p = e / K;                       // packed row (= output col)
  int col = (int)(e - p * K);
  long r = (long)(((p >> 4) & 3) * 512 + ((p >> 6) << 4) + (p & 15));
  const float* src = (col < w1) ? (W1 + r * (long)w1 + col)
                                : (W2 + r * (long)w2 + (col - w1));
  const float4 v = *reinterpret_cast<const float4*>(src);
  short4 o; o.x=f2bf(v.x); o.y=f2bf(v.y); o.z=f2bf(v.z); o.w=f2bf(v.w);
  *reinterpret_cast<short4*>(dst + e) = o;
}

// packed bias: out[p] = b1[r] (+ b2[r])
__global__ void packbias_kernel(const float* __restrict__ b1, const float* __restrict__ b2,
                                float* __restrict__ o, int n)
{
  int p = blockIdx.x * blockDim.x + threadIdx.x;
  if (p >= n) return;
  int r = ((p >> 4) & 3) * 512 + ((p >> 6) << 4) + (p & 15);
  float v = b1[r];
  if (b2) v += b2[r];
  o[p] = v;
}

// ---------------- slot write + pos_emb add + bf16 staging -------------------
__global__ void slot_update_kernel(const float* __restrict__ slots,
                                   const float* __restrict__ v,
                                   const float* __restrict__ pos_emb,
                                   const int* __restrict__ ptr,
                                   const int* __restrict__ ev,
                                   float* __restrict__ new_slots,
                                   short* __restrict__ slots_pe)
{
  size_t i = (size_t)blockIdx.x * blockDim.x + threadIdx.x;   // one per 4 elems
  size_t e = i * 4;
  int d = (int)(e & (kD - 1));
  size_t bs = e >> 9;
  int s = (int)(bs & (kS - 1));
  size_t b = bs >> 4;
  float4 val;
  if (ev[b] && (ptr[b] == s)) val = *reinterpret_cast<const float4*>(v + (b << 9) + d);
  else                        val = *reinterpret_cast<const float4*>(slots + e);
  *reinterpret_cast<float4*>(new_slots + e) = val;
  const float4 pe = *reinterpret_cast<const float4*>(pos_emb + ((size_t)s << 9) + d);
  short4 o;
  o.x = f2bf(val.x + pe.x); o.y = f2bf(val.y + pe.y);
  o.z = f2bf(val.z + pe.z); o.w = f2bf(val.w + pe.w);
  *reinterpret_cast<short4*>(slots_pe + e) = o;
}

// ---------------- persistent slot-fuser LSTM chain --------------------------
// Grid MUST be kChainBlocks x 256. Block (bx,by) owns rows [bx*128,+128),
// packed cols [by*64,+64). c in registers. h is written to per-step RENAMED
// buffers (write-once/read-once): consumer caches never hold stale lines, so
// NO fences / cache maintenance are needed. The (bx,*) group of 32 blocks is
// XCD-local (vid swizzle), so h stays in one L2. Store->flag ordering comes
// from __syncthreads' vmcnt(0) drain + atomics executing at L2.
__global__ __launch_bounds__(256, 4)
void chain_kernel(const short* __restrict__ slots_pe,
                  const short* __restrict__ W,      // kG x 1024 gate-packed
                  const float* __restrict__ bias,   // kG packed
                  short* __restrict__ hsteps,       // kS bufs of kB*kH bf16
                  float* __restrict__ hmem,
                  unsigned* __restrict__ barrier_ctr)   // 15*32 ctrs, 64B stride
{
  __shared__ short As[128 * 64];
  __shared__ short Ws[64 * 64];
  const int tid  = threadIdx.x;
  const int wave = tid >> 6;
  const int lane = tid & 63;

  // XCD-chunked swizzle: bx-group (32 blocks) lands on one XCD
  const int vid = (blockIdx.x & 7) * 128 + (blockIdx.x >> 3);
  const int bx  = vid >> 5;          // nby = 32
  const int by  = vid & 31;
  const int row0 = bx * 128;
  const int col0 = by * 64;

  const int srow   = tid >> 3;                       // 0..31
  const int scol   = (tid & 7) * 8;                  // linear chunk (LDS dest)
  const int schunk = (((tid >> 3) ^ tid) & 7) * 8;   // swizzled chunk (gl src)

  float bv[4];
  #pragma unroll
  for (int n = 0; n < 4; ++n)
    bv[n] = bias[col0 + n * 16 + (lane & 15)];
  const int hcol = by * 16 + (lane & 15);

  float c_reg[2][4];
  #pragma unroll
  for (int m = 0; m < 2; ++m)
    #pragma unroll
    for (int r = 0; r < 4; ++r) c_reg[m][r] = 0.f;

  for (int s = 0; s < kS; ++s) {
    f32x4_t acc[2][4];
    #pragma unroll
    for (int m = 0; m < 2; ++m)
      #pragma unroll
      for (int n = 0; n < 4; ++n) acc[m][n] = {0.f, 0.f, 0.f, 0.f};

    // ---- phase A: input half (K = 0..511 of packed W) ----
    const short* A = slots_pe + (size_t)s * kD;
    for (int k0 = 0; k0 < 512; k0 += 64) {
      __syncthreads();
      #pragma unroll
      for (int j = 0; j < 4; ++j) {
        const int arow = j * 32 + srow;
        const short* asrc = A + (size_t)(row0 + arow) * (kS * kD) + k0 + schunk;
        __builtin_amdgcn_global_load_lds(
            (const __attribute__((address_space(1))) void*)asrc,
            (__attribute__((address_space(3))) void*)&As[arow * 64 + scol], 16, 0, 0);
      }
      #pragma unroll
      for (int j = 0; j < 2; ++j) {
        const int wrow = j * 32 + srow;
        const short* wsrc = W + (size_t)(col0 + wrow) * 1024 + k0 + schunk;
        __builtin_amdgcn_global_load_lds(
            (const __attribute__((address_space(1))) void*)wsrc,
            (__attribute__((address_space(3))) void*)&Ws[wrow * 64 + scol], 16, 0, 0);
      }
      __syncthreads();
      #pragma unroll
      for (int kk = 0; kk < 64; kk += 32) {
        bf16x8_t af[2], bfr[4];
        const int kcol = kk + (lane >> 4) * 8;
        const int ar = wave * 32 + (lane & 15);
        const int br = lane & 15;
        #pragma unroll
        for (int m = 0; m < 2; ++m)
          af[m] = *reinterpret_cast<const bf16x8_t*>(&As[swz(ar + m * 16, kcol)]);
        #pragma unroll
        for (int n = 0; n < 4; ++n)
          bfr[n] = *reinterpret_cast<const bf16x8_t*>(&Ws[swz(br + n * 16, kcol)]);
        #pragma unroll
        for (int m = 0; m < 2; ++m)
          #pragma unroll
          for (int n = 0; n < 4; ++n)
            acc[m][n] = __builtin_amdgcn_mfma_f32_16x16x32_bf16(af[m], bfr[n], acc[m][n], 0, 0, 0);
      }
    }

    // ---- phase B: recurrent half (K = 512..1023 of packed W) ----
    if (s > 0) {
      const short* Hp = hsteps + (size_t)(s - 1) * kB * kH;
      // per-bx-group barrier (32 blocks, XCD-local). Relaxed everywhere:
      // __syncthreads drained vmcnt(0) (h stores complete at L2), atomics
      // execute at L2, renamed buffers make stale caching impossible.
      unsigned* ctr = barrier_ctr + (((s - 1) * 32 + bx) << 4);
      __syncthreads();
      if (tid == 0) {
        __hip_atomic_fetch_add(ctr, 1u, __ATOMIC_RELAXED, __HIP_MEMORY_SCOPE_AGENT);
        while (__hip_atomic_load(ctr, __ATOMIC_RELAXED, __HIP_MEMORY_SCOPE_AGENT) < 32u)
          __builtin_amdgcn_s_sleep(2);
      }
      __syncthreads();
      for (int k0 = 0; k0 < 512; k0 += 64) {
        __syncthreads();
        #pragma unroll
        for (int j = 0; j < 4; ++j) {
          const int arow = j * 32 + srow;
          const short* asrc = Hp + (size_t)(row0 + arow) * kH + k0 + schunk;
          __builtin_amdgcn_global_load_lds(
              (const __attribute__((address_space(1))) void*)asrc,
              (__attribute__((address_space(3))) void*)&As[arow * 64 + scol], 16, 0, 0);
        }
        #pragma unroll
        for (int j = 0; j < 2; ++j) {
          const int wrow = j * 32 + srow;
          const short* wsrc = W + (size_t)(col0 + wrow) * 1024 + 512 + k0 + schunk;
          __builtin_amdgcn_global_load_lds(
              (const __attribute__((address_space(1))) void*)wsrc,
              (__attribute__((address_space(3))) void*)&Ws[wrow * 64 + scol], 16, 0, 0);
        }
        __syncthreads();
        #pragma unroll
        for (int kk = 0; kk < 64; kk += 32) {
          bf16x8_t af[2], bfr[4];
          const int kcol = kk + (lane >> 4) * 8;
          const int ar = wave * 32 + (lane & 15);
          const int br = lane & 15;
          #pragma unroll
          for (int m = 0; m < 2; ++m)
            af[m] = *reinterpret_cast<const bf16x8_t*>(&As[swz(ar + m * 16, kcol)]);
          #pragma unroll
          for (int n = 0; n < 4; ++n)
            bfr[n] = *reinterpret_cast<const bf16x8_t*>(&Ws[swz(br + n * 16, kcol)]);
          #pragma unroll
          for (int m = 0; m < 2; ++m)
            #pragma unroll
            for (int n = 0; n < 4; ++n)
              acc[m][n] = __builtin_amdgcn_mfma_f32_16x16x32_bf16(af[m], bfr[n], acc[m][n], 0, 0, 0);
        }
      }
    }

    // ---- epilogue: LSTM cell update, c in registers ----
    short* Hout = hsteps + (size_t)s * kB * kH;
    #pragma unroll
    for (int m = 0; m < 2; ++m) {
      const int rbase = row0 + wave * 32 + m * 16 + (lane >> 4) * 4;
      #pragma unroll
      for (int r = 0; r < 4; ++r) {
        const size_t idx = (size_t)(rbase + r) * kH + hcol;
        const float gi = acc[m][0][r] + bv[0];
        const float gf = acc[m][1][r] + bv[1];
        const float gg = acc[m][2][r] + bv[2];
        const float go = acc[m][3][r] + bv[3];
        const float cn = sigm(gf) * c_reg[m][r] + sigm(gi) * tanhf(gg);
        const float hn = sigm(go) * tanhf(cn);
        c_reg[m][r] = cn;
        Hout[idx] = f2bf(hn);
        if (s == kS - 1) hmem[idx] = hn;
      }
    }
  }
}

// ---------------- bf16 MFMA GEMM with fused epilogue (v-GEMM / outer) ------
// Tile 128x64, BK=64. 4 waves all in M. Grid 1-D XCD-chunk swizzled.
// mode 0: C = A@W^T + bias
// mode 2: outer LSTM ew: c_in -> h_out, c_out  (W gate-packed)
__global__ __launch_bounds__(256, 4)
void gemm_fused_kernel(const short* __restrict__ A0, int lda0,
                       const short* __restrict__ A1, int lda1,
                       const short* __restrict__ A2, int lda2,
                       int nseg, const short* __restrict__ W, int ldw,
                       const float* __restrict__ bias, int mode, int nby,
                       float* __restrict__ C, int ldc,
                       const float* __restrict__ c_in,
                       float* __restrict__ h_out, float* __restrict__ c_out)
{
  __shared__ short As[128 * 64];
  __shared__ short Ws[64 * 64];
  const int tid  = threadIdx.x;
  const int wave = tid >> 6;
  const int lane = tid & 63;

  const int nb  = gridDim.x;
  const int vid = (blockIdx.x & 7) * (nb >> 3) + (blockIdx.x >> 3);
  const int bx  = vid / nby;
  const int by  = vid - bx * nby;
  const int row0 = bx * 128;
  const int col0 = by * 64;
  const int K = nseg << 9;

  f32x4_t acc[2][4];
  #pragma unroll
  for (int m = 0; m < 2; ++m)
    #pragma unroll
    for (int n = 0; n < 4; ++n)
      acc[m][n] = {0.f, 0.f, 0.f, 0.f};

  const int srow   = tid >> 3;
  const int scol   = (tid & 7) * 8;
  const int schunk = (((tid >> 3) ^ tid) & 7) * 8;

  for (int k0 = 0; k0 < K; k0 += 64) {
    const int seg = k0 >> 9;
    const int ks  = k0 & 511;
    const short* Ap = (seg == 0) ? A0 : ((seg == 1) ? A1 : A2);
    const int   lda = (seg == 0) ? lda0 : ((seg == 1) ? lda1 : lda2);
    __syncthreads();
    #pragma unroll
    for (int j = 0; j < 4; ++j) {
      const int arow = j * 32 + srow;
      const short* asrc = Ap + (size_t)(row0 + arow) * lda + ks + schunk;
      __builtin_amdgcn_global_load_lds(
          (const __attribute__((address_space(1))) void*)asrc,
          (__attribute__((address_space(3))) void*)&As[arow * 64 + scol], 16, 0, 0);
    }
    #pragma unroll
    for (int j = 0; j < 2; ++j) {
      const int wrow = j * 32 + srow;
      const short* wsrc = W + (size_t)(col0 + wrow) * ldw + k0 + schunk;
      __builtin_amdgcn_global_load_lds(
          (const __attribute__((address_space(1))) void*)wsrc,
          (__attribute__((address_space(3))) void*)&Ws[wrow * 64 + scol], 16, 0, 0);
    }
    __syncthreads();
    #pragma unroll
    for (int kk = 0; kk < 64; kk += 32) {
      bf16x8_t af[2], bfr[4];
      const int kcol = kk + (lane >> 4) * 8;
      const int ar = wave * 32 + (lane & 15);
      const int br = lane & 15;
      #pragma unroll
      for (int m = 0; m < 2; ++m)
        af[m] = *reinterpret_cast<const bf16x8_t*>(&As[swz(ar + m * 16, kcol)]);
      #pragma unroll
      for (int n = 0; n < 4; ++n)
        bfr[n] = *reinterpret_cast<const bf16x8_t*>(&Ws[swz(br + n * 16, kcol)]);
      #pragma unroll
      for (int m = 0; m < 2; ++m)
        #pragma unroll
        for (int n = 0; n < 4; ++n)
          acc[m][n] = __builtin_amdgcn_mfma_f32_16x16x32_bf16(af[m], bfr[n], acc[m][n], 0, 0, 0);
    }
  }

  float bv[4];
  #pragma unroll
  for (int n = 0; n < 4; ++n)
    bv[n] = bias[col0 + n * 16 + (lane & 15)];

  if (mode == 0) {
    #pragma unroll
    for (int n = 0; n < 4; ++n) {
      const int col = col0 + n * 16 + (lane & 15);
      #pragma unroll
      for (int m = 0; m < 2; ++m) {
        const int rbase = row0 + wave * 32 + m * 16 + (lane >> 4) * 4;
        #pragma unroll
        for (int r = 0; r < 4; ++r)
          C[(size_t)(rbase + r) * ldc + col] = acc[m][n][r] + bv[n];
      }
    }
    return;
  }

  const int hcol = (col0 >> 6) * 16 + (lane & 15);
  #pragma unroll
  for (int m = 0; m < 2; ++m) {
    const int rbase = row0 + wave * 32 + m * 16 + (lane >> 4) * 4;
    #pragma unroll
    for (int r = 0; r < 4; ++r) {
      const size_t idx = (size_t)(rbase + r) * kH + hcol;
      const float gi = acc[m][0][r] + bv[0];
      const float gf = acc[m][1][r] + bv[1];
      const float gg = acc[m][2][r] + bv[2];
      const float go = acc[m][3][r] + bv[3];
      const float cn = sigm(gf) * c_in[idx] + sigm(gi) * tanhf(gg);
      const float hn = sigm(go) * tanhf(cn);
      c_out[idx] = cn;
      h_out[idx] = hn;
    }
  }
}

// ============================================================================
extern "C" void kernel_launch(void* const* d_in, const int* in_sizes, int n_in,
                              void* d_out, int out_size, void* d_ws, size_t ws_size,
                              hipStream_t stream)
{
  const float* x_t      = (const float*)d_in[0];
  const float* h_lstm   = (const float*)d_in[1];
  const float* c_lstm   = (const float*)d_in[2];
  const float* slots    = (const float*)d_in[3];
  const int*   ptr      = (const int*)  d_in[4];
  const float* value_W  = (const float*)d_in[5];
  const float* value_b  = (const float*)d_in[6];
  const float* ed_W     = (const float*)d_in[7];
  const float* ed_b     = (const float*)d_in[8];
  const float* pos_emb  = (const float*)d_in[9];
  const float* lstm_Wih = (const float*)d_in[10];
  const float* lstm_Whh = (const float*)d_in[11];
  const float* lstm_bih = (const float*)d_in[12];
  const float* lstm_bhh = (const float*)d_in[13];
  const float* Wih      = (const float*)d_in[14];
  const float* bih      = (const float*)d_in[15];
  const float* Whh      = (const float*)d_in[16];

  float* out       = (float*)d_out;
  float* h_new     = out;
  float* c_new     = out + (size_t)kB * kH;
  float* h_mem     = out + (size_t)2 * kB * kH;
  float* new_slots = out + (size_t)3 * kB * kH;
  float* new_ptr   = out + (size_t)3 * kB * kH + (size_t)kB * kS * kD;

  // workspace layout (bytes)
  char* ws = (char*)d_ws;
  size_t off = 0;
  auto alloc = [&](size_t bytes) { void* p = ws + off; off += (bytes + 255) & ~(size_t)255; return p; };
  int*      ev        = (int*)     alloc((size_t)kB * 4);
  unsigned* bar       = (unsigned*)alloc((size_t)15 * 32 * 16 * 4);  // 64B-strided
  short*    x_b       = (short*)   alloc((size_t)kB * kD * 2);
  short*    hlstm_b   = (short*)   alloc((size_t)kB * kH * 2);
  short*    vW_b      = (short*)   alloc((size_t)kD * kD * 2);
  short*    stepW_b   = (short*)   alloc((size_t)kG * (kD + kH) * 2);
  float*    stepBias  = (float*)   alloc((size_t)kG * 4);
  short*    outerW_b  = (short*)   alloc((size_t)kG * (kD + kH + kH) * 2);
  float*    outerBias = (float*)   alloc((size_t)kG * 4);
  float*    v_f32     = (float*)   alloc((size_t)kB * kD * 4);
  short*    hsteps    = (short*)   alloc((size_t)kS * kB * kH * 2);  // 64 MB renamed
  short*    slots_pe  = (short*)   alloc((size_t)kB * kS * kD * 2);
  (void)ws_size; (void)in_sizes; (void)n_in; (void)out_size;

  // 0. barrier counters -> 0 (one-shot per call; ws not re-poisoned between replays)
  bar_init_kernel<<<(15 * 32 * 16 + 255) / 256, 256, 0, stream>>>(bar, 15 * 32 * 16);

  // 1. event flags + new_ptr (f32 exact)
  event_kernel<<<kB / 4, 256, 0, stream>>>(x_t, ed_W, ed_b, ptr, ev, new_ptr);

  // 2. conversions / packing
  f2b_kernel<<<(kB * kD / 4 + 255) / 256, 256, 0, stream>>>(x_t, x_b, kB * kD / 4);
  f2b_kernel<<<(kB * kH / 4 + 255) / 256, 256, 0, stream>>>(h_lstm, hlstm_b, kB * kH / 4);
  f2b_kernel<<<(kD * kD / 4 + 255) / 256, 256, 0, stream>>>(value_W, vW_b, kD * kD / 4);
  packw_gates_kernel<<<(kG * 1024 / 4 + 255) / 256, 256, 0, stream>>>(
      lstm_Wih, kD, lstm_Whh, kH, stepW_b, kG * 1024 / 4);
  packw_gates_kernel<<<(kG * 1536 / 4 + 255) / 256, 256, 0, stream>>>(
      Wih, kD + kH, Whh, kH, outerW_b, kG * 1536 / 4);
  packbias_kernel<<<(kG + 255) / 256, 256, 0, stream>>>(lstm_bih, lstm_bhh, stepBias, kG);
  packbias_kernel<<<(kG + 255) / 256, 256, 0, stream>>>(bih, nullptr, outerBias, kG);

  // 3. v = x @ value_W^T + value_b  (mode 0)
  gemm_fused_kernel<<<(kB / 128) * (kD / 64), 256, 0, stream>>>(
      x_b, kD, nullptr, 0, nullptr, 0, 1, vW_b, kD, value_b, 0, kD / 64,
      v_f32, kD, nullptr, nullptr, nullptr);

  // 4. new_slots (f32 out) + slots_pe bf16 staging
  slot_update_kernel<<<(int)((size_t)kB * kS * kD / 4 / 256), 256, 0, stream>>>(
      slots, v_f32, pos_emb, ptr, ev, new_slots, slots_pe);

  // 5. persistent slot-fuser chain (1024 blocks, 4/CU, XCD-local group barriers)
  chain_kernel<<<kChainBlocks, 256, 0, stream>>>(
      slots_pe, stepW_b, stepBias, hsteps, h_mem, bar);

  // 6. outer LSTM fused: gates = [x | h_mem | h_lstm] @ [Wih|Whh]^T + bih
  //    h after step 15 lives in hsteps[15].
  gemm_fused_kernel<<<(kB / 128) * (kG / 64), 256, 0, stream>>>(
      x_b, kD, hsteps + (size_t)(kS - 1) * kB * kH, kH, hlstm_b, kH, 3,
      outerW_b, kD + kH + kH, outerBias, 2, kG / 64,
      nullptr, 0, c_lstm, h_new, c_new);
}

// Round 9
// 803.691 us; speedup vs baseline: 4.1977x; 1.0169x over previous
//
#include <hip/hip_runtime.h>
#include <hip/hip_bf16.h>

// Problem constants (fixed by reference)
constexpr int kB = 4096;
constexpr int kD = 512;
constexpr int kH = 512;
constexpr int kS = 16;
constexpr int kG = 2048;   // 4*H
constexpr int kChainBlocks = 256;    // 1 block/CU (128 KB LDS forces it), exact fit.

typedef __attribute__((ext_vector_type(8))) short bf16x8_t;
typedef __attribute__((ext_vector_type(4))) float f32x4_t;

__device__ __forceinline__ short f2bf(float x) {
  __hip_bfloat16 h = __float2bfloat16(x);
  return *reinterpret_cast<short*>(&h);
}
__device__ __forceinline__ float sigm(float x) { return 1.0f / (1.0f + expf(-x)); }

// LDS XOR swizzle for [rows][64] staging tiles (16B-chunk ^ row&7)
__device__ __forceinline__ int swz(int row, int kElem) {
  return row * 64 + (((kElem >> 3) ^ (row & 7)) << 3);
}
// LDS XOR swizzle for the chain's [64][1024] W-slice
__device__ __forceinline__ int wswz(int wrow, int kElem) {
  return wrow * 1024 + ((((kElem >> 3) ^ wrow) & 7) << 3) + (kElem & ~63) ;
}

__global__ void bar_init_kernel(unsigned* __restrict__ ctr, int n)
{
  int i = blockIdx.x * blockDim.x + threadIdx.x;
  if (i < n) ctr[i] = 0u;
}

// ---------------- event detection + new_ptr (precision-critical: f32) ------
__global__ void event_kernel(const float* __restrict__ x,
                             const float* __restrict__ edW,
                             const float* __restrict__ edb,
                             const int* __restrict__ ptr,
                             int* __restrict__ ev,
                             float* __restrict__ newptr_out)
{
  int b = blockIdx.x * 4 + (threadIdx.x >> 6);
  int lane = threadIdx.x & 63;
  const float* xr = x + (size_t)b * kD;
  float sum = 0.f;
  for (int k = lane; k < kD; k += 64) sum += xr[k] * edW[k];
  #pragma unroll
  for (int off = 32; off; off >>= 1) sum += __shfl_down(sum, off, 64);
  if (lane == 0) {
    float e = sigm(sum + edb[0]);
    int evt = (e > 0.85f) ? 1 : 0;
    ev[b] = evt;
    newptr_out[b] = (float)((ptr[b] + evt) & (kS - 1));
  }
}

// ---------------- f32 -> bf16 convert (vectorized) --------------------------
__global__ void f2b_kernel(const float* __restrict__ src, short* __restrict__ dst, int n4)
{
  int i = blockIdx.x * blockDim.x + threadIdx.x;
  if (i >= n4) return;
  const float4 v = reinterpret_cast<const float4*>(src)[i];
  short4 o;
  o.x = f2bf(v.x); o.y = f2bf(v.y); o.z = f2bf(v.z); o.w = f2bf(v.w);
  reinterpret_cast<short4*>(dst)[i] = o;
}

// ---------------- pack [W1 | W2] rows into bf16 with gate interleave --------
// Packed output col p:  h = (p>>6)*16 + (p&15),  gate = (p>>4)&3.
// Source row r = gate*512 + h (PyTorch i,f,g,o order).
__global__ void packw_gates_kernel(const float* __restrict__ W1, int w1,
                                   const float* __restrict__ W2, int w2,
                                   short* __restrict__ dst, int total4)
{
  int i = blockIdx.x * blockDim.x + threadIdx.x;
  if (i >= total4) return;
  long e = (long)i * 4;
  int K = w1 + w2;
  long p = e / K;                       // packed row (= output col)
  int col = (int)(e - p * K);
  long r = (long)(((p >> 4) & 3) * 512 + ((p >> 6) << 4) + (p & 15));
  const float* src = (col < w1) ? (W1 + r * (long)w1 + col)
                                : (W2 + r * (long)w2 + (col - w1));
  const float4 v = *reinterpret_cast<const float4*>(src);
  short4 o; o.x=f2bf(v.x); o.y=f2bf(v.y); o.z=f2bf(v.z); o.w=f2bf(v.w);
  *reinterpret_cast<short4*>(dst + e) = o;
}

// packed bias: out[p] = b1[r] (+ b2[r])
__global__ void packbias_kernel(const float* __restrict__ b1, const float* __restrict__ b2,
                                float* __restrict__ o, int n)
{
  int p = blockIdx.x * blockDim.x + threadIdx.x;
  if (p >= n) return;
  int r = ((p >> 4) & 3) * 512 + ((p >> 6) << 4) + (p & 15);
  float v = b1[r];
  if (b2) v += b2[r];
  o[p] = v;
}

// ---------------- slot write + pos_emb add + bf16 staging -------------------
__global__ void slot_update_kernel(const float* __restrict__ slots,
                                   const float* __restrict__ v,
                                   const float* __restrict__ pos_emb,
                                   const int* __restrict__ ptr,
                                   const int* __restrict__ ev,
                                   float* __restrict__ new_slots,
                                   short* __restrict__ slots_pe)
{
  size_t i = (size_t)blockIdx.x * blockDim.x + threadIdx.x;   // one per 4 elems
  size_t e = i * 4;
  int d = (int)(e & (kD - 1));
  size_t bs = e >> 9;
  int s = (int)(bs & (kS - 1));
  size_t b = bs >> 4;
  float4 val;
  if (ev[b] && (ptr[b] == s)) val = *reinterpret_cast<const float4*>(v + (b << 9) + d);
  else                        val = *reinterpret_cast<const float4*>(slots + e);
  *reinterpret_cast<float4*>(new_slots + e) = val;
  const float4 pe = *reinterpret_cast<const float4*>(pos_emb + ((size_t)s << 9) + d);
  short4 o;
  o.x = f2bf(val.x + pe.x); o.y = f2bf(val.y + pe.y);
  o.z = f2bf(val.z + pe.z); o.w = f2bf(val.w + pe.w);
  *reinterpret_cast<short4*>(slots_pe + e) = o;
}

// ---------------- persistent slot-fuser LSTM chain (W pinned in LDS) --------
// Grid MUST be 256 blocks x 512 threads (1 block/CU; 128 KB LDS). Block
// (bx=blockIdx&7, by=blockIdx>>3) owns rows [bx*512,+512), packed cols
// [by*64,+64). Its 64x1024 W slice lives in LDS for all 16 steps. A and H
// are loaded global->register fragments (no LDS staging). h goes to per-step
// renamed buffers. Barrier: 8 groups of 32 blocks; RELEASE arrive (flush
// dirty h lines), RELAXED spin, no acquire needed (write-once buffers).
__global__ __launch_bounds__(512, 2)
void chain_kernel(const short* __restrict__ slots_pe,
                  const short* __restrict__ W,      // kG x 1024 gate-packed
                  const float* __restrict__ bias,   // kG packed
                  short* __restrict__ hsteps,       // kS bufs of kB*kH bf16
                  float* __restrict__ hmem,
                  unsigned* __restrict__ barrier_ctr)   // 15*8 ctrs, 64B stride
{
  __shared__ short Wlds[64 * 1024];   // 128 KB
  const int tid  = threadIdx.x;
  const int wave = tid >> 6;          // 0..7
  const int lane = tid & 63;

  const int bx  = blockIdx.x & 7;    // same-bx group lands on one XCD (perf)
  const int by  = blockIdx.x >> 3;   // 0..31
  const int row0 = bx * 512;
  const int col0 = by * 64;

  // ---- stage W slice (64 rows x 1024 k) into LDS once, pre-swizzled src ----
  #pragma unroll
  for (int r8 = 0; r8 < 8; ++r8) {
    const int wrow = r8 * 8 + wave;            // 0..63
    #pragma unroll
    for (int p = 0; p < 2; ++p) {
      const int c = p * 64 + lane;             // global 16B-chunk 0..127
      const short* src = W + (size_t)(col0 + wrow) * 1024 + ((c ^ (wrow & 7)) << 3);
      __builtin_amdgcn_global_load_lds(
          (const __attribute__((address_space(1))) void*)src,
          (__attribute__((address_space(3))) void*)&Wlds[wrow * 1024 + p * 512],
          16, 0, 0);
    }
  }
  __syncthreads();

  float bv[4];
  #pragma unroll
  for (int n = 0; n < 4; ++n)
    bv[n] = bias[col0 + n * 16 + (lane & 15)];
  const int hcol = by * 16 + (lane & 15);
  const int rowsbase = row0 + wave * 64;       // wave's 64 rows
  const int arow = rowsbase + (lane & 15);     // this lane's A-frag row
  const int klane = (lane >> 4) << 3;          // k sub-offset 0/8/16/24

  float c_reg[4][4];
  #pragma unroll
  for (int m = 0; m < 4; ++m)
    #pragma unroll
    for (int r = 0; r < 4; ++r) c_reg[m][r] = 0.f;

  for (int s = 0; s < kS; ++s) {
    f32x4_t acc[4][4];
    #pragma unroll
    for (int m = 0; m < 4; ++m)
      #pragma unroll
      for (int n = 0; n < 4; ++n) acc[m][n] = {0.f, 0.f, 0.f, 0.f};

    // ---- phase A: input half. A = slots_pe[:, s, :], row stride kS*kD ----
    {
      const short* Ap = slots_pe + (size_t)s * kD + (size_t)arow * (kS * kD);
      #pragma unroll 4
      for (int k0 = 0; k0 < 512; k0 += 32) {
        const int kc = k0 + klane;
        bf16x8_t af[4], bfr[4];
        #pragma unroll
        for (int m = 0; m < 4; ++m)
          af[m] = *reinterpret_cast<const bf16x8_t*>(Ap + (size_t)(m * 16) * (kS * kD) + kc);
        #pragma unroll
        for (int n = 0; n < 4; ++n)
          bfr[n] = *reinterpret_cast<const bf16x8_t*>(&Wlds[wswz((lane & 15) + n * 16, kc)]);
        #pragma unroll
        for (int m = 0; m < 4; ++m)
          #pragma unroll
          for (int n = 0; n < 4; ++n)
            acc[m][n] = __builtin_amdgcn_mfma_f32_16x16x32_bf16(af[m], bfr[n], acc[m][n], 0, 0, 0);
      }
    }

    // ---- phase B: recurrent half ----
    if (s > 0) {
      unsigned* ctr = barrier_ctr + (((s - 1) * 8 + bx) << 4);
      __syncthreads();   // drains each wave's vmcnt(0): h stores of s-1 done
      if (tid == 0) {
        __hip_atomic_fetch_add(ctr, 1u, __ATOMIC_RELEASE, __HIP_MEMORY_SCOPE_AGENT);
        while (__hip_atomic_load(ctr, __ATOMIC_RELAXED, __HIP_MEMORY_SCOPE_AGENT) < 32u)
          __builtin_amdgcn_s_sleep(2);
      }
      __syncthreads();
      const short* Hp = hsteps + (size_t)(s - 1) * kB * kH + (size_t)arow * kH;
      #pragma unroll 4
      for (int k0 = 0; k0 < 512; k0 += 32) {
        const int kc = k0 + klane;
        bf16x8_t af[4], bfr[4];
        #pragma unroll
        for (int m = 0; m < 4; ++m)
          af[m] = *reinterpret_cast<const bf16x8_t*>(Hp + (size_t)(m * 16) * kH + kc);
        #pragma unroll
        for (int n = 0; n < 4; ++n)
          bfr[n] = *reinterpret_cast<const bf16x8_t*>(&Wlds[wswz((lane & 15) + n * 16, 512 + kc)]);
        #pragma unroll
        for (int m = 0; m < 4; ++m)
          #pragma unroll
          for (int n = 0; n < 4; ++n)
            acc[m][n] = __builtin_amdgcn_mfma_f32_16x16x32_bf16(af[m], bfr[n], acc[m][n], 0, 0, 0);
      }
    }

    // ---- epilogue: LSTM cell update, c in registers ----
    short* Hout = hsteps + (size_t)s * kB * kH;
    #pragma unroll
    for (int m = 0; m < 4; ++m) {
      const int rbase = rowsbase + m * 16 + (lane >> 4) * 4;
      #pragma unroll
      for (int r = 0; r < 4; ++r) {
        const size_t idx = (size_t)(rbase + r) * kH + hcol;
        const float gi = acc[m][0][r] + bv[0];
        const float gf = acc[m][1][r] + bv[1];
        const float gg = acc[m][2][r] + bv[2];
        const float go = acc[m][3][r] + bv[3];
        const float cn = sigm(gf) * c_reg[m][r] + sigm(gi) * tanhf(gg);
        const float hn = sigm(go) * tanhf(cn);
        c_reg[m][r] = cn;
        Hout[idx] = f2bf(hn);
        if (s == kS - 1) hmem[idx] = hn;
      }
    }
  }
}

// ---------------- bf16 MFMA GEMM with fused epilogue (v-GEMM / outer) ------
// Tile 128x64, BK=64. 4 waves all in M. Grid 1-D XCD-chunk swizzled.
// mode 0: C = A@W^T + bias
// mode 2: outer LSTM ew: c_in -> h_out, c_out  (W gate-packed)
__global__ __launch_bounds__(256, 4)
void gemm_fused_kernel(const short* __restrict__ A0, int lda0,
                       const short* __restrict__ A1, int lda1,
                       const short* __restrict__ A2, int lda2,
                       int nseg, const short* __restrict__ W, int ldw,
                       const float* __restrict__ bias, int mode, int nby,
                       float* __restrict__ C, int ldc,
                       const float* __restrict__ c_in,
                       float* __restrict__ h_out, float* __restrict__ c_out)
{
  __shared__ short As[128 * 64];
  __shared__ short Ws[64 * 64];
  const int tid  = threadIdx.x;
  const int wave = tid >> 6;
  const int lane = tid & 63;

  const int nb  = gridDim.x;
  const int vid = (blockIdx.x & 7) * (nb >> 3) + (blockIdx.x >> 3);
  const int bx  = vid / nby;
  const int by  = vid - bx * nby;
  const int row0 = bx * 128;
  const int col0 = by * 64;
  const int K = nseg << 9;

  f32x4_t acc[2][4];
  #pragma unroll
  for (int m = 0; m < 2; ++m)
    #pragma unroll
    for (int n = 0; n < 4; ++n)
      acc[m][n] = {0.f, 0.f, 0.f, 0.f};

  const int srow   = tid >> 3;
  const int scol   = (tid & 7) * 8;
  const int schunk = (((tid >> 3) ^ tid) & 7) * 8;

  for (int k0 = 0; k0 < K; k0 += 64) {
    const int seg = k0 >> 9;
    const int ks  = k0 & 511;
    const short* Ap = (seg == 0) ? A0 : ((seg == 1) ? A1 : A2);
    const int   lda = (seg == 0) ? lda0 : ((seg == 1) ? lda1 : lda2);
    __syncthreads();
    #pragma unroll
    for (int j = 0; j < 4; ++j) {
      const int r = j * 32 + srow;
      const short* asrc = Ap + (size_t)(row0 + r) * lda + ks + schunk;
      __builtin_amdgcn_global_load_lds(
          (const __attribute__((address_space(1))) void*)asrc,
          (__attribute__((address_space(3))) void*)&As[r * 64 + scol], 16, 0, 0);
    }
    #pragma unroll
    for (int j = 0; j < 2; ++j) {
      const int r = j * 32 + srow;
      const short* wsrc = W + (size_t)(col0 + r) * ldw + k0 + schunk;
      __builtin_amdgcn_global_load_lds(
          (const __attribute__((address_space(1))) void*)wsrc,
          (__attribute__((address_space(3))) void*)&Ws[r * 64 + scol], 16, 0, 0);
    }
    __syncthreads();
    #pragma unroll
    for (int kk = 0; kk < 64; kk += 32) {
      bf16x8_t af[2], bfr[4];
      const int kcol = kk + (lane >> 4) * 8;
      const int ar = wave * 32 + (lane & 15);
      const int br = lane & 15;
      #pragma unroll
      for (int m = 0; m < 2; ++m)
        af[m] = *reinterpret_cast<const bf16x8_t*>(&As[swz(ar + m * 16, kcol)]);
      #pragma unroll
      for (int n = 0; n < 4; ++n)
        bfr[n] = *reinterpret_cast<const bf16x8_t*>(&Ws[swz(br + n * 16, kcol)]);
      #pragma unroll
      for (int m = 0; m < 2; ++m)
        #pragma unroll
        for (int n = 0; n < 4; ++n)
          acc[m][n] = __builtin_amdgcn_mfma_f32_16x16x32_bf16(af[m], bfr[n], acc[m][n], 0, 0, 0);
    }
  }

  float bv[4];
  #pragma unroll
  for (int n = 0; n < 4; ++n)
    bv[n] = bias[col0 + n * 16 + (lane & 15)];

  if (mode == 0) {
    #pragma unroll
    for (int n = 0; n < 4; ++n) {
      const int col = col0 + n * 16 + (lane & 15);
      #pragma unroll
      for (int m = 0; m < 2; ++m) {
        const int rbase = row0 + wave * 32 + m * 16 + (lane >> 4) * 4;
        #pragma unroll
        for (int r = 0; r < 4; ++r)
          C[(size_t)(rbase + r) * ldc + col] = acc[m][n][r] + bv[n];
      }
    }
    return;
  }

  const int hcol = (col0 >> 6) * 16 + (lane & 15);
  #pragma unroll
  for (int m = 0; m < 2; ++m) {
    const int rbase = row0 + wave * 32 + m * 16 + (lane >> 4) * 4;
    #pragma unroll
    for (int r = 0; r < 4; ++r) {
      const size_t idx = (size_t)(rbase + r) * kH + hcol;
      const float gi = acc[m][0][r] + bv[0];
      const float gf = acc[m][1][r] + bv[1];
      const float gg = acc[m][2][r] + bv[2];
      const float go = acc[m][3][r] + bv[3];
      const float cn = sigm(gf) * c_in[idx] + sigm(gi) * tanhf(gg);
      const float hn = sigm(go) * tanhf(cn);
      c_out[idx] = cn;
      h_out[idx] = hn;
    }
  }
}

// ============================================================================
extern "C" void kernel_launch(void* const* d_in, const int* in_sizes, int n_in,
                              void* d_out, int out_size, void* d_ws, size_t ws_size,
                              hipStream_t stream)
{
  const float* x_t      = (const float*)d_in[0];
  const float* h_lstm   = (const float*)d_in[1];
  const float* c_lstm   = (const float*)d_in[2];
  const float* slots    = (const float*)d_in[3];
  const int*   ptr      = (const int*)  d_in[4];
  const float* value_W  = (const float*)d_in[5];
  const float* value_b  = (const float*)d_in[6];
  const float* ed_W     = (const float*)d_in[7];
  const float* ed_b     = (const float*)d_in[8];
  const float* pos_emb  = (const float*)d_in[9];
  const float* lstm_Wih = (const float*)d_in[10];
  const float* lstm_Whh = (const float*)d_in[11];
  const float* lstm_bih = (const float*)d_in[12];
  const float* lstm_bhh = (const float*)d_in[13];
  const float* Wih      = (const float*)d_in[14];
  const float* bih      = (const float*)d_in[15];
  const float* Whh      = (const float*)d_in[16];

  float* out       = (float*)d_out;
  float* h_new     = out;
  float* c_new     = out + (size_t)kB * kH;
  float* h_mem     = out + (size_t)2 * kB * kH;
  float* new_slots = out + (size_t)3 * kB * kH;
  float* new_ptr   = out + (size_t)3 * kB * kH + (size_t)kB * kS * kD;

  // workspace layout (bytes)
  char* ws = (char*)d_ws;
  size_t off = 0;
  auto alloc = [&](size_t bytes) { void* p = ws + off; off += (bytes + 255) & ~(size_t)255; return p; };
  int*      ev        = (int*)     alloc((size_t)kB * 4);
  unsigned* bar       = (unsigned*)alloc((size_t)15 * 8 * 16 * 4);  // 64B-strided
  short*    x_b       = (short*)   alloc((size_t)kB * kD * 2);
  short*    hlstm_b   = (short*)   alloc((size_t)kB * kH * 2);
  short*    vW_b      = (short*)   alloc((size_t)kD * kD * 2);
  short*    stepW_b   = (short*)   alloc((size_t)kG * (kD + kH) * 2);
  float*    stepBias  = (float*)   alloc((size_t)kG * 4);
  short*    outerW_b  = (short*)   alloc((size_t)kG * (kD + kH + kH) * 2);
  float*    outerBias = (float*)   alloc((size_t)kG * 4);
  float*    v_f32     = (float*)   alloc((size_t)kB * kD * 4);
  short*    hsteps    = (short*)   alloc((size_t)kS * kB * kH * 2);  // 64 MB renamed
  short*    slots_pe  = (short*)   alloc((size_t)kB * kS * kD * 2);
  (void)ws_size; (void)in_sizes; (void)n_in; (void)out_size;

  // 0. barrier counters -> 0 (one-shot per call; ws not re-poisoned between replays)
  bar_init_kernel<<<(15 * 8 * 16 + 255) / 256, 256, 0, stream>>>(bar, 15 * 8 * 16);

  // 1. event flags + new_ptr (f32 exact)
  event_kernel<<<kB / 4, 256, 0, stream>>>(x_t, ed_W, ed_b, ptr, ev, new_ptr);

  // 2. conversions / packing
  f2b_kernel<<<(kB * kD / 4 + 255) / 256, 256, 0, stream>>>(x_t, x_b, kB * kD / 4);
  f2b_kernel<<<(kB * kH / 4 + 255) / 256, 256, 0, stream>>>(h_lstm, hlstm_b, kB * kH / 4);
  f2b_kernel<<<(kD * kD / 4 + 255) / 256, 256, 0, stream>>>(value_W, vW_b, kD * kD / 4);
  packw_gates_kernel<<<(kG * 1024 / 4 + 255) / 256, 256, 0, stream>>>(
      lstm_Wih, kD, lstm_Whh, kH, stepW_b, kG * 1024 / 4);
  packw_gates_kernel<<<(kG * 1536 / 4 + 255) / 256, 256, 0, stream>>>(
      Wih, kD + kH, Whh, kH, outerW_b, kG * 1536 / 4);
  packbias_kernel<<<(kG + 255) / 256, 256, 0, stream>>>(lstm_bih, lstm_bhh, stepBias, kG);
  packbias_kernel<<<(kG + 255) / 256, 256, 0, stream>>>(bih, nullptr, outerBias, kG);

  // 3. v = x @ value_W^T + value_b  (mode 0)
  gemm_fused_kernel<<<(kB / 128) * (kD / 64), 256, 0, stream>>>(
      x_b, kD, nullptr, 0, nullptr, 0, 1, vW_b, kD, value_b, 0, kD / 64,
      v_f32, kD, nullptr, nullptr, nullptr);

  // 4. new_slots (f32 out) + slots_pe bf16 staging
  slot_update_kernel<<<(int)((size_t)kB * kS * kD / 4 / 256), 256, 0, stream>>>(
      slots, v_f32, pos_emb, ptr, ev, new_slots, slots_pe);

  // 5. persistent slot-fuser chain (256 blocks x 512 thr, 1/CU, W in LDS)
  chain_kernel<<<kChainBlocks, 512, 0, stream>>>(
      slots_pe, stepW_b, stepBias, hsteps, h_mem, bar);

  // 6. outer LSTM fused: gates = [x | h_mem | h_lstm] @ [Wih|Whh]^T + bih
  //    h after step 15 lives in hsteps[15].
  gemm_fused_kernel<<<(kB / 128) * (kG / 64), 256, 0, stream>>>(
      x_b, kD, hsteps + (size_t)(kS - 1) * kB * kH, kH, hlstm_b, kH, 3,
      outerW_b, kD + kH + kH, outerBias, 2, kG / 64,
      nullptr, 0, c_lstm, h_new, c_new);
}

// Round 10
// 753.308 us; speedup vs baseline: 4.4785x; 1.0669x over previous
//
#include <hip/hip_runtime.h>
#include <hip/hip_bf16.h>

// Problem constants (fixed by reference)
constexpr int kB = 4096;
constexpr int kD = 512;
constexpr int kH = 512;
constexpr int kS = 16;
constexpr int kG = 2048;   // 4*H
constexpr int kChainBlocks = 256;    // 1 block/CU (128 KB LDS forces it), exact fit.

typedef __attribute__((ext_vector_type(8))) short bf16x8_t;
typedef __attribute__((ext_vector_type(4))) float f32x4_t;

__device__ __forceinline__ short f2bf(float x) {
  __hip_bfloat16 h = __float2bfloat16(x);
  return *reinterpret_cast<short*>(&h);
}
// precise sigmoid: event threshold decision only
__device__ __forceinline__ float sigm_precise(float x) { return 1.0f / (1.0f + expf(-x)); }
// fast math for LSTM epilogues (error ~1e-6, threshold 0.3)
__device__ __forceinline__ float sigm(float x) { return 1.0f / (1.0f + __expf(-x)); }
__device__ __forceinline__ float ftanh(float x) {
  x = fminf(15.0f, fmaxf(-15.0f, x));
  const float e = __expf(2.0f * x);
  return (e - 1.0f) / (e + 1.0f);
}

// LDS XOR swizzle for [rows][64] staging tiles (16B-chunk ^ row&7)
__device__ __forceinline__ int swz(int row, int kElem) {
  return row * 64 + (((kElem >> 3) ^ (row & 7)) << 3);
}
// LDS XOR swizzle for the chain's [64][1024] W-slice
__device__ __forceinline__ int wswz(int wrow, int kElem) {
  return wrow * 1024 + ((((kElem >> 3) ^ wrow) & 7) << 3) + (kElem & ~63);
}

__global__ void bar_init_kernel(unsigned* __restrict__ ctr, int n)
{
  int i = blockIdx.x * blockDim.x + threadIdx.x;
  if (i < n) ctr[i] = 0u;
}

// ---------------- event detection + new_ptr (precision-critical: f32) ------
__global__ void event_kernel(const float* __restrict__ x,
                             const float* __restrict__ edW,
                             const float* __restrict__ edb,
                             const int* __restrict__ ptr,
                             int* __restrict__ ev,
                             float* __restrict__ newptr_out)
{
  int b = blockIdx.x * 4 + (threadIdx.x >> 6);
  int lane = threadIdx.x & 63;
  const float* xr = x + (size_t)b * kD;
  float sum = 0.f;
  for (int k = lane; k < kD; k += 64) sum += xr[k] * edW[k];
  #pragma unroll
  for (int off = 32; off; off >>= 1) sum += __shfl_down(sum, off, 64);
  if (lane == 0) {
    float e = sigm_precise(sum + edb[0]);
    int evt = (e > 0.85f) ? 1 : 0;
    ev[b] = evt;
    newptr_out[b] = (float)((ptr[b] + evt) & (kS - 1));
  }
}

// ---------------- f32 -> bf16 convert (vectorized) --------------------------
__global__ void f2b_kernel(const float* __restrict__ src, short* __restrict__ dst, int n4)
{
  int i = blockIdx.x * blockDim.x + threadIdx.x;
  if (i >= n4) return;
  const float4 v = reinterpret_cast<const float4*>(src)[i];
  short4 o;
  o.x = f2bf(v.x); o.y = f2bf(v.y); o.z = f2bf(v.z); o.w = f2bf(v.w);
  reinterpret_cast<short4*>(dst)[i] = o;
}

// ---------------- pack [W1 | W2] rows into bf16 with gate interleave --------
// Packed output col p:  h = (p>>6)*16 + (p&15),  gate = (p>>4)&3.
// Source row r = gate*512 + h (PyTorch i,f,g,o order).
__global__ void packw_gates_kernel(const float* __restrict__ W1, int w1,
                                   const float* __restrict__ W2, int w2,
                                   short* __restrict__ dst, int total4)
{
  int i = blockIdx.x * blockDim.x + threadIdx.x;
  if (i >= total4) return;
  long e = (long)i * 4;
  int K = w1 + w2;
  long p = e / K;                       // packed row (= output col)
  int col = (int)(e - p * K);
  long r = (long)(((p >> 4) & 3) * 512 + ((p >> 6) << 4) + (p & 15));
  const float* src = (col < w1) ? (W1 + r * (long)w1 + col)
                                : (W2 + r * (long)w2 + (col - w1));
  const float4 v = *reinterpret_cast<const float4*>(src);
  short4 o; o.x=f2bf(v.x); o.y=f2bf(v.y); o.z=f2bf(v.z); o.w=f2bf(v.w);
  *reinterpret_cast<short4*>(dst + e) = o;
}

// packed bias: out[p] = b1[r] (+ b2[r])
__global__ void packbias_kernel(const float* __restrict__ b1, const float* __restrict__ b2,
                                float* __restrict__ o, int n)
{
  int p = blockIdx.x * blockDim.x + threadIdx.x;
  if (p >= n) return;
  int r = ((p >> 4) & 3) * 512 + ((p >> 6) << 4) + (p & 15);
  float v = b1[r];
  if (b2) v += b2[r];
  o[p] = v;
}

// ---------------- slot write + pos_emb add + bf16 staging -------------------
__global__ void slot_update_kernel(const float* __restrict__ slots,
                                   const float* __restrict__ v,
                                   const float* __restrict__ pos_emb,
                                   const int* __restrict__ ptr,
                                   const int* __restrict__ ev,
                                   float* __restrict__ new_slots,
                                   short* __restrict__ slots_pe)
{
  size_t i = (size_t)blockIdx.x * blockDim.x + threadIdx.x;   // one per 4 elems
  size_t e = i * 4;
  int d = (int)(e & (kD - 1));
  size_t bs = e >> 9;
  int s = (int)(bs & (kS - 1));
  size_t b = bs >> 4;
  float4 val;
  if (ev[b] && (ptr[b] == s)) val = *reinterpret_cast<const float4*>(v + (b << 9) + d);
  else                        val = *reinterpret_cast<const float4*>(slots + e);
  *reinterpret_cast<float4*>(new_slots + e) = val;
  const float4 pe = *reinterpret_cast<const float4*>(pos_emb + ((size_t)s << 9) + d);
  short4 o;
  o.x = f2bf(val.x + pe.x); o.y = f2bf(val.y + pe.y);
  o.z = f2bf(val.z + pe.z); o.w = f2bf(val.w + pe.w);
  *reinterpret_cast<short4*>(slots_pe + e) = o;
}

// ---------------- persistent slot-fuser LSTM chain (W pinned in LDS) --------
// Grid MUST be 256 blocks x 512 threads (1 block/CU; 128 KB LDS). Block
// (bx=blockIdx&7, by=blockIdx>>3) owns rows [bx*512,+512), packed cols
// [by*64,+64). Its 64x1024 W slice lives in LDS for all 16 steps. A/H are
// loaded global->register with a DEPTH-2 prefetch pipeline (L2-hit ~250 cyc
// hidden under ~2 iters of MFMA issue at 2 waves/SIMD). h goes to per-step
// renamed buffers (no fences). Barrier: 8 groups of 32 blocks; RELEASE
// arrival posted right after the epilogue store-drain (early), RELAXED spin.
__global__ __launch_bounds__(512, 2)
void chain_kernel(const short* __restrict__ slots_pe,
                  const short* __restrict__ W,      // kG x 1024 gate-packed
                  const float* __restrict__ bias,   // kG packed
                  short* __restrict__ hsteps,       // kS bufs of kB*kH bf16
                  float* __restrict__ hmem,
                  unsigned* __restrict__ barrier_ctr)   // 15*8 ctrs, 64B stride
{
  __shared__ short Wlds[64 * 1024];   // 128 KB
  const int tid  = threadIdx.x;
  const int wave = tid >> 6;          // 0..7
  const int lane = tid & 63;

  const int bx  = blockIdx.x & 7;    // same-bx group lands on one XCD (perf)
  const int by  = blockIdx.x >> 3;   // 0..31
  const int row0 = bx * 512;
  const int col0 = by * 64;

  // ---- stage W slice (64 rows x 1024 k) into LDS once, pre-swizzled src ----
  #pragma unroll
  for (int r8 = 0; r8 < 8; ++r8) {
    const int wrow = r8 * 8 + wave;            // 0..63
    #pragma unroll
    for (int p = 0; p < 2; ++p) {
      const int c = p * 64 + lane;             // global 16B-chunk 0..127
      const short* src = W + (size_t)(col0 + wrow) * 1024 + ((c ^ (wrow & 7)) << 3);
      __builtin_amdgcn_global_load_lds(
          (const __attribute__((address_space(1))) void*)src,
          (__attribute__((address_space(3))) void*)&Wlds[wrow * 1024 + p * 512],
          16, 0, 0);
    }
  }
  __syncthreads();

  float bv[4];
  #pragma unroll
  for (int n = 0; n < 4; ++n)
    bv[n] = bias[col0 + n * 16 + (lane & 15)];
  const int hcol = by * 16 + (lane & 15);
  const int rowsbase = row0 + wave * 64;       // wave's 64 rows
  const int arow = rowsbase + (lane & 15);     // this lane's A-frag row
  const int klane = (lane >> 4) << 3;          // k sub-offset 0/8/16/24

  float c_reg[4][4];
  #pragma unroll
  for (int m = 0; m < 4; ++m)
    #pragma unroll
    for (int r = 0; r < 4; ++r) c_reg[m][r] = 0.f;

  for (int s = 0; s < kS; ++s) {
    f32x4_t acc[4][4];
    #pragma unroll
    for (int m = 0; m < 4; ++m)
      #pragma unroll
      for (int n = 0; n < 4; ++n) acc[m][n] = {0.f, 0.f, 0.f, 0.f};

    // ---- phase A: input half (row stride kS*kD), depth-2 prefetch ----
    {
      const short* Ap = slots_pe + (size_t)s * kD + (size_t)arow * (kS * kD);
      bf16x8_t a0[4], a1[4];
      #pragma unroll
      for (int m = 0; m < 4; ++m) {
        a0[m] = *reinterpret_cast<const bf16x8_t*>(Ap + (size_t)(m * 16) * (kS * kD) + klane);
        a1[m] = *reinterpret_cast<const bf16x8_t*>(Ap + (size_t)(m * 16) * (kS * kD) + 32 + klane);
      }
      #pragma unroll 4
      for (int k0 = 0; k0 < 512; k0 += 32) {
        bf16x8_t an[4];
        if (k0 + 64 < 512) {
          #pragma unroll
          for (int m = 0; m < 4; ++m)
            an[m] = *reinterpret_cast<const bf16x8_t*>(
                Ap + (size_t)(m * 16) * (kS * kD) + k0 + 64 + klane);
        }
        const int kc = k0 + klane;
        bf16x8_t bfr[4];
        #pragma unroll
        for (int n = 0; n < 4; ++n)
          bfr[n] = *reinterpret_cast<const bf16x8_t*>(&Wlds[wswz((lane & 15) + n * 16, kc)]);
        #pragma unroll
        for (int m = 0; m < 4; ++m)
          #pragma unroll
          for (int n = 0; n < 4; ++n)
            acc[m][n] = __builtin_amdgcn_mfma_f32_16x16x32_bf16(a0[m], bfr[n], acc[m][n], 0, 0, 0);
        #pragma unroll
        for (int m = 0; m < 4; ++m) { a0[m] = a1[m]; a1[m] = an[m]; }
      }
    }

    // ---- phase B: recurrent half, after group barrier ----
    if (s > 0) {
      unsigned* ctr = barrier_ctr + (((s - 1) * 8 + bx) << 4);
      if (tid == 0) {
        while (__hip_atomic_load(ctr, __ATOMIC_RELAXED, __HIP_MEMORY_SCOPE_AGENT) < 32u)
          __builtin_amdgcn_s_sleep(2);
      }
      __syncthreads();
      const short* Hp = hsteps + (size_t)(s - 1) * kB * kH + (size_t)arow * kH;
      bf16x8_t a0[4], a1[4];
      #pragma unroll
      for (int m = 0; m < 4; ++m) {
        a0[m] = *reinterpret_cast<const bf16x8_t*>(Hp + (size_t)(m * 16) * kH + klane);
        a1[m] = *reinterpret_cast<const bf16x8_t*>(Hp + (size_t)(m * 16) * kH + 32 + klane);
      }
      #pragma unroll 4
      for (int k0 = 0; k0 < 512; k0 += 32) {
        bf16x8_t an[4];
        if (k0 + 64 < 512) {
          #pragma unroll
          for (int m = 0; m < 4; ++m)
            an[m] = *reinterpret_cast<const bf16x8_t*>(
                Hp + (size_t)(m * 16) * kH + k0 + 64 + klane);
        }
        const int kc = k0 + klane;
        bf16x8_t bfr[4];
        #pragma unroll
        for (int n = 0; n < 4; ++n)
          bfr[n] = *reinterpret_cast<const bf16x8_t*>(&Wlds[wswz((lane & 15) + n * 16, 512 + kc)]);
        #pragma unroll
        for (int m = 0; m < 4; ++m)
          #pragma unroll
          for (int n = 0; n < 4; ++n)
            acc[m][n] = __builtin_amdgcn_mfma_f32_16x16x32_bf16(a0[m], bfr[n], acc[m][n], 0, 0, 0);
        #pragma unroll
        for (int m = 0; m < 4; ++m) { a0[m] = a1[m]; a1[m] = an[m]; }
      }
    }

    // ---- epilogue: LSTM cell update (fast math), c in registers ----
    short* Hout = hsteps + (size_t)s * kB * kH;
    #pragma unroll
    for (int m = 0; m < 4; ++m) {
      const int rbase = rowsbase + m * 16 + (lane >> 4) * 4;
      #pragma unroll
      for (int r = 0; r < 4; ++r) {
        const size_t idx = (size_t)(rbase + r) * kH + hcol;
        const float gi = acc[m][0][r] + bv[0];
        const float gf = acc[m][1][r] + bv[1];
        const float gg = acc[m][2][r] + bv[2];
        const float go = acc[m][3][r] + bv[3];
        const float cn = sigm(gf) * c_reg[m][r] + sigm(gi) * ftanh(gg);
        const float hn = sigm(go) * ftanh(cn);
        c_reg[m][r] = cn;
        Hout[idx] = f2bf(hn);
        if (s == kS - 1) hmem[idx] = hn;
      }
    }

    // ---- early arrival: h(s) complete after this drain ----
    if (s < kS - 1) {
      __syncthreads();   // each wave's h stores drained (vmcnt0 before barrier)
      if (tid == 0)
        __hip_atomic_fetch_add(barrier_ctr + ((s * 8 + bx) << 4), 1u,
                               __ATOMIC_RELEASE, __HIP_MEMORY_SCOPE_AGENT);
    }
  }
}

// ---------------- bf16 MFMA GEMM with fused epilogue (v-GEMM / outer) ------
// Tile 128x64, BK=64. 4 waves all in M. Grid 1-D XCD-chunk swizzled.
// mode 0: C = A@W^T + bias
// mode 2: outer LSTM ew: c_in -> h_out, c_out  (W gate-packed)
__global__ __launch_bounds__(256, 4)
void gemm_fused_kernel(const short* __restrict__ A0, int lda0,
                       const short* __restrict__ A1, int lda1,
                       const short* __restrict__ A2, int lda2,
                       int nseg, const short* __restrict__ W, int ldw,
                       const float* __restrict__ bias, int mode, int nby,
                       float* __restrict__ C, int ldc,
                       const float* __restrict__ c_in,
                       float* __restrict__ h_out, float* __restrict__ c_out)
{
  __shared__ short As[128 * 64];
  __shared__ short Ws[64 * 64];
  const int tid  = threadIdx.x;
  const int wave = tid >> 6;
  const int lane = tid & 63;

  const int nb  = gridDim.x;
  const int vid = (blockIdx.x & 7) * (nb >> 3) + (blockIdx.x >> 3);
  const int bx  = vid / nby;
  const int by  = vid - bx * nby;
  const int row0 = bx * 128;
  const int col0 = by * 64;
  const int K = nseg << 9;

  f32x4_t acc[2][4];
  #pragma unroll
  for (int m = 0; m < 2; ++m)
    #pragma unroll
    for (int n = 0; n < 4; ++n)
      acc[m][n] = {0.f, 0.f, 0.f, 0.f};

  const int srow   = tid >> 3;
  const int scol   = (tid & 7) * 8;
  const int schunk = (((tid >> 3) ^ tid) & 7) * 8;

  for (int k0 = 0; k0 < K; k0 += 64) {
    const int seg = k0 >> 9;
    const int ks  = k0 & 511;
    const short* Ap = (seg == 0) ? A0 : ((seg == 1) ? A1 : A2);
    const int   lda = (seg == 0) ? lda0 : ((seg == 1) ? lda1 : lda2);
    __syncthreads();
    #pragma unroll
    for (int j = 0; j < 4; ++j) {
      const int r = j * 32 + srow;
      const short* asrc = Ap + (size_t)(row0 + r) * lda + ks + schunk;
      __builtin_amdgcn_global_load_lds(
          (const __attribute__((address_space(1))) void*)asrc,
          (__attribute__((address_space(3))) void*)&As[r * 64 + scol], 16, 0, 0);
    }
    #pragma unroll
    for (int j = 0; j < 2; ++j) {
      const int r = j * 32 + srow;
      const short* wsrc = W + (size_t)(col0 + r) * ldw + k0 + schunk;
      __builtin_amdgcn_global_load_lds(
          (const __attribute__((address_space(1))) void*)wsrc,
          (__attribute__((address_space(3))) void*)&Ws[r * 64 + scol], 16, 0, 0);
    }
    __syncthreads();
    #pragma unroll
    for (int kk = 0; kk < 64; kk += 32) {
      bf16x8_t af[2], bfr[4];
      const int kcol = kk + (lane >> 4) * 8;
      const int ar = wave * 32 + (lane & 15);
      const int br = lane & 15;
      #pragma unroll
      for (int m = 0; m < 2; ++m)
        af[m] = *reinterpret_cast<const bf16x8_t*>(&As[swz(ar + m * 16, kcol)]);
      #pragma unroll
      for (int n = 0; n < 4; ++n)
        bfr[n] = *reinterpret_cast<const bf16x8_t*>(&Ws[swz(br + n * 16, kcol)]);
      #pragma unroll
      for (int m = 0; m < 2; ++m)
        #pragma unroll
        for (int n = 0; n < 4; ++n)
          acc[m][n] = __builtin_amdgcn_mfma_f32_16x16x32_bf16(af[m], bfr[n], acc[m][n], 0, 0, 0);
    }
  }

  float bv[4];
  #pragma unroll
  for (int n = 0; n < 4; ++n)
    bv[n] = bias[col0 + n * 16 + (lane & 15)];

  if (mode == 0) {
    #pragma unroll
    for (int n = 0; n < 4; ++n) {
      const int col = col0 + n * 16 + (lane & 15);
      #pragma unroll
      for (int m = 0; m < 2; ++m) {
        const int rbase = row0 + wave * 32 + m * 16 + (lane >> 4) * 4;
        #pragma unroll
        for (int r = 0; r < 4; ++r)
          C[(size_t)(rbase + r) * ldc + col] = acc[m][n][r] + bv[n];
      }
    }
    return;
  }

  const int hcol = (col0 >> 6) * 16 + (lane & 15);
  #pragma unroll
  for (int m = 0; m < 2; ++m) {
    const int rbase = row0 + wave * 32 + m * 16 + (lane >> 4) * 4;
    #pragma unroll
    for (int r = 0; r < 4; ++r) {
      const size_t idx = (size_t)(rbase + r) * kH + hcol;
      const float gi = acc[m][0][r] + bv[0];
      const float gf = acc[m][1][r] + bv[1];
      const float gg = acc[m][2][r] + bv[2];
      const float go = acc[m][3][r] + bv[3];
      const float cn = sigm(gf) * c_in[idx] + sigm(gi) * ftanh(gg);
      const float hn = sigm(go) * ftanh(cn);
      c_out[idx] = cn;
      h_out[idx] = hn;
    }
  }
}

// ============================================================================
extern "C" void kernel_launch(void* const* d_in, const int* in_sizes, int n_in,
                              void* d_out, int out_size, void* d_ws, size_t ws_size,
                              hipStream_t stream)
{
  const float* x_t      = (const float*)d_in[0];
  const float* h_lstm   = (const float*)d_in[1];
  const float* c_lstm   = (const float*)d_in[2];
  const float* slots    = (const float*)d_in[3];
  const int*   ptr      = (const int*)  d_in[4];
  const float* value_W  = (const float*)d_in[5];
  const float* value_b  = (const float*)d_in[6];
  const float* ed_W     = (const float*)d_in[7];
  const float* ed_b     = (const float*)d_in[8];
  const float* pos_emb  = (const float*)d_in[9];
  const float* lstm_Wih = (const float*)d_in[10];
  const float* lstm_Whh = (const float*)d_in[11];
  const float* lstm_bih = (const float*)d_in[12];
  const float* lstm_bhh = (const float*)d_in[13];
  const float* Wih      = (const float*)d_in[14];
  const float* bih      = (const float*)d_in[15];
  const float* Whh      = (const float*)d_in[16];

  float* out       = (float*)d_out;
  float* h_new     = out;
  float* c_new     = out + (size_t)kB * kH;
  float* h_mem     = out + (size_t)2 * kB * kH;
  float* new_slots = out + (size_t)3 * kB * kH;
  float* new_ptr   = out + (size_t)3 * kB * kH + (size_t)kB * kS * kD;

  // workspace layout (bytes)
  char* ws = (char*)d_ws;
  size_t off = 0;
  auto alloc = [&](size_t bytes) { void* p = ws + off; off += (bytes + 255) & ~(size_t)255; return p; };
  int*      ev        = (int*)     alloc((size_t)kB * 4);
  unsigned* bar       = (unsigned*)alloc((size_t)15 * 8 * 16 * 4);  // 64B-strided
  short*    x_b       = (short*)   alloc((size_t)kB * kD * 2);
  short*    hlstm_b   = (short*)   alloc((size_t)kB * kH * 2);
  short*    vW_b      = (short*)   alloc((size_t)kD * kD * 2);
  short*    stepW_b   = (short*)   alloc((size_t)kG * (kD + kH) * 2);
  float*    stepBias  = (float*)   alloc((size_t)kG * 4);
  short*    outerW_b  = (short*)   alloc((size_t)kG * (kD + kH + kH) * 2);
  float*    outerBias = (float*)   alloc((size_t)kG * 4);
  float*    v_f32     = (float*)   alloc((size_t)kB * kD * 4);
  short*    hsteps    = (short*)   alloc((size_t)kS * kB * kH * 2);  // 64 MB renamed
  short*    slots_pe  = (short*)   alloc((size_t)kB * kS * kD * 2);
  (void)ws_size; (void)in_sizes; (void)n_in; (void)out_size;

  // 0. barrier counters -> 0 (one-shot per call; ws not re-poisoned between replays)
  bar_init_kernel<<<(15 * 8 * 16 + 255) / 256, 256, 0, stream>>>(bar, 15 * 8 * 16);

  // 1. event flags + new_ptr (f32 exact)
  event_kernel<<<kB / 4, 256, 0, stream>>>(x_t, ed_W, ed_b, ptr, ev, new_ptr);

  // 2. conversions / packing
  f2b_kernel<<<(kB * kD / 4 + 255) / 256, 256, 0, stream>>>(x_t, x_b, kB * kD / 4);
  f2b_kernel<<<(kB * kH / 4 + 255) / 256, 256, 0, stream>>>(h_lstm, hlstm_b, kB * kH / 4);
  f2b_kernel<<<(kD * kD / 4 + 255) / 256, 256, 0, stream>>>(value_W, vW_b, kD * kD / 4);
  packw_gates_kernel<<<(kG * 1024 / 4 + 255) / 256, 256, 0, stream>>>(
      lstm_Wih, kD, lstm_Whh, kH, stepW_b, kG * 1024 / 4);
  packw_gates_kernel<<<(kG * 1536 / 4 + 255) / 256, 256, 0, stream>>>(
      Wih, kD + kH, Whh, kH, outerW_b, kG * 1536 / 4);
  packbias_kernel<<<(kG + 255) / 256, 256, 0, stream>>>(lstm_bih, lstm_bhh, stepBias, kG);
  packbias_kernel<<<(kG + 255) / 256, 256, 0, stream>>>(bih, nullptr, outerBias, kG);

  // 3. v = x @ value_W^T + value_b  (mode 0)
  gemm_fused_kernel<<<(kB / 128) * (kD / 64), 256, 0, stream>>>(
      x_b, kD, nullptr, 0, nullptr, 0, 1, vW_b, kD, value_b, 0, kD / 64,
      v_f32, kD, nullptr, nullptr, nullptr);

  // 4. new_slots (f32 out) + slots_pe bf16 staging
  slot_update_kernel<<<(int)((size_t)kB * kS * kD / 4 / 256), 256, 0, stream>>>(
      slots, v_f32, pos_emb, ptr, ev, new_slots, slots_pe);

  // 5. persistent slot-fuser chain (256 blocks x 512 thr, 1/CU, W in LDS)
  chain_kernel<<<kChainBlocks, 512, 0, stream>>>(
      slots_pe, stepW_b, stepBias, hsteps, h_mem, bar);

  // 6. outer LSTM fused: gates = [x | h_mem | h_lstm] @ [Wih|Whh]^T + bih
  //    h after step 15 lives in hsteps[15].
  gemm_fused_kernel<<<(kB / 128) * (kG / 64), 256, 0, stream>>>(
      x_b, kD, hsteps + (size_t)(kS - 1) * kB * kH, kH, hlstm_b, kH, 3,
      outerW_b, kD + kH + kH, outerBias, 2, kG / 64,
      nullptr, 0, c_lstm, h_new, c_new);
}